// Round 15
// baseline (377.462 us; speedup 1.0000x reference)
//
#include <hip/hip_runtime.h>
#include <hip/hip_bf16.h>
#include <math.h>

#define DIMC 768
#define HEADS 12
#define HD 64
#define EXPERTS 8
#define HID 3072
#define BB 8
#define NN 196
#define TT (BB*NN)      // 1568
#define CAP_ROWS 4224   // multiple of 64, >= 2*TT + 8*64 headroom
#define LN_EPS 1e-5f

typedef float f32x4_t __attribute__((ext_vector_type(4)));
typedef short bf16x8_t __attribute__((ext_vector_type(8)));
typedef unsigned short u16x8_t __attribute__((ext_vector_type(8)));

__device__ __forceinline__ unsigned short f2bf(float f) {
    unsigned int u = __float_as_uint(f);
    u += 0x7FFFu + ((u >> 16) & 1u);   // round-to-nearest-even
    return (unsigned short)(u >> 16);
}
__device__ __forceinline__ float bf2f(unsigned short u) {
    return __uint_as_float(((unsigned int)u) << 16);
}

// async global->LDS, 16B per lane; LDS dest = wave-uniform base + lane*16 (linear)
__device__ __forceinline__ void gl_lds16(const void* g, void* l) {
    __builtin_amdgcn_global_load_lds(
        (const __attribute__((address_space(1))) unsigned int*)g,
        (__attribute__((address_space(3))) unsigned int*)l, 16, 0, 0);
}

// bijective XCD-chunked remap (m204): physical bid -> logical L
__device__ __forceinline__ int xcd_remap(int pbid, int nwg) {
    int q = nwg >> 3, r8 = nwg & 7;
    int xcd = pbid & 7, slot = pbid >> 3;
    return (xcd < r8) ? xcd * (q + 1) + slot
                      : r8 * (q + 1) + (xcd - r8) * q + slot;
}

// ---------------- LayerNorm (+ optional fused gate): one block per token, 256 threads ----------------
template<int GATE>
__global__ void ln_kernel_t(const float* __restrict__ x, const float* __restrict__ g,
                            const float* __restrict__ b,
                            unsigned short* __restrict__ out_hi,
                            unsigned short* __restrict__ out_lo,
                            const float* __restrict__ gw, int* __restrict__ tok_e,
                            float* __restrict__ tok_g, int* __restrict__ counts) {
    int t = blockIdx.x;
    const float* xr = x + (size_t)t * DIMC;
    int tid = threadIdx.x;
    float v0 = xr[tid], v1 = xr[tid + 256], v2 = xr[tid + 512];
    __shared__ float red[256];
    red[tid] = v0 + v1 + v2;
    __syncthreads();
    for (int off = 128; off > 0; off >>= 1) {
        if (tid < off) red[tid] += red[tid + off];
        __syncthreads();
    }
    float mu = red[0] * (1.0f / DIMC);
    __syncthreads();
    float d0 = v0 - mu, d1 = v1 - mu, d2 = v2 - mu;
    red[tid] = d0*d0 + d1*d1 + d2*d2;
    __syncthreads();
    for (int off = 128; off > 0; off >>= 1) {
        if (tid < off) red[tid] += red[tid + off];
        __syncthreads();
    }
    float rstd = rsqrtf(red[0] * (1.0f / DIMC) + LN_EPS);
    float o0 = d0 * rstd * g[tid]       + b[tid];
    float o1 = d1 * rstd * g[tid + 256] + b[tid + 256];
    float o2 = d2 * rstd * g[tid + 512] + b[tid + 512];
    {
        unsigned short* o = out_hi + (size_t)t * DIMC;
        unsigned short h0 = f2bf(o0), h1 = f2bf(o1), h2 = f2bf(o2);
        o[tid] = h0; o[tid + 256] = h1; o[tid + 512] = h2;
        if (out_lo) {
            unsigned short* ol = out_lo + (size_t)t * DIMC;
            ol[tid]       = f2bf(o0 - bf2f(h0));
            ol[tid + 256] = f2bf(o1 - bf2f(h1));
            ol[tid + 512] = f2bf(o2 - bf2f(h2));
        }
    }
    if (GATE) {
        float p[8];
        const float* g0r = gw + (size_t)tid * 8;
        const float* g1r = gw + ((size_t)tid + 256) * 8;
        const float* g2r = gw + ((size_t)tid + 512) * 8;
        #pragma unroll
        for (int e = 0; e < 8; ++e)
            p[e] = o0 * g0r[e] + o1 * g1r[e] + o2 * g2r[e];
        #pragma unroll
        for (int off = 32; off > 0; off >>= 1)
            #pragma unroll
            for (int e = 0; e < 8; ++e) p[e] += __shfl_xor(p[e], off, 64);
        __shared__ float redw[4][8];
        int lane = tid & 63, w = tid >> 6;
        if (lane == 0) {
            #pragma unroll
            for (int e = 0; e < 8; ++e) redw[w][e] = p[e];
        }
        __syncthreads();
        if (tid == 0) {
            float lg[8];
            #pragma unroll
            for (int e = 0; e < 8; ++e)
                lg[e] = redw[0][e] + redw[1][e] + redw[2][e] + redw[3][e];
            int e0 = 0; float l0 = lg[0];
            #pragma unroll
            for (int e = 1; e < 8; ++e) if (lg[e] > l0) { l0 = lg[e]; e0 = e; }
            int e1 = -1; float l1 = -3e38f;
            #pragma unroll
            for (int e = 0; e < 8; ++e) if (e != e0 && lg[e] > l1) { l1 = lg[e]; e1 = e; }
            float pp = expf(l1 - l0);
            float ga = 1.f / (1.f + pp);
            float gb = pp / (1.f + pp);
            tok_e[t*2] = e0; tok_e[t*2+1] = e1;
            tok_g[t*2] = ga; tok_g[t*2+1] = gb;
            atomicAdd(&counts[e0], 1);
            atomicAdd(&counts[e1], 1);
        }
    }
}

// ---------------- MFMA attention, split-precision, 512 threads / 8 waves (validated r11) ----------------
__global__ void attn_mfma_kernel(const float* __restrict__ qkv,
                                 unsigned short* __restrict__ ao_h,
                                 unsigned short* __restrict__ ao_l) {
    __shared__ char psb[64 * 896];                         // 56 KB, swizzled fp32 [64][224]
    __shared__ unsigned short QsH[64 * 64], QsL[64 * 64];
    __shared__ unsigned short KsH[64 * 64], KsL[64 * 64];

    int bh = blockIdx.x;
    int b = bh / HEADS, h = bh % HEADS;
    int q0 = blockIdx.y * 64;
    const float* base = qkv + (size_t)b * NN * 2304 + h * 64;

    int tid = threadIdx.x;                 // 0..511
    int sr = tid >> 3, sq = tid & 7;
    int lane = tid & 63;
    int wid = tid >> 6;
    int wm = (wid >> 2) * 32;
    int wn = (wid & 3) * 16;
    int lrow = lane & 15;
    int lq = lane >> 4;
    int colb_base = lq * 16;

    {
        int r = sr;
        int n = q0 + r;
        float v[8] = {0.f,0.f,0.f,0.f,0.f,0.f,0.f,0.f};
        if (n < NN) {
            float4 a0 = *(const float4*)(base + (size_t)n * 2304 + sq * 8);
            float4 a1 = *(const float4*)(base + (size_t)n * 2304 + sq * 8 + 4);
            v[0]=a0.x; v[1]=a0.y; v[2]=a0.z; v[3]=a0.w;
            v[4]=a1.x; v[5]=a1.y; v[6]=a1.z; v[7]=a1.w;
        }
        u16x8_t hv, lv;
        #pragma unroll
        for (int t = 0; t < 8; ++t) {
            unsigned short hh = f2bf(v[t]);
            hv[t] = hh; lv[t] = f2bf(v[t] - bf2f(hh));
        }
        int off = r * 128 + ((sq * 16) ^ ((r & 7) << 4));
        *(u16x8_t*)((char*)QsH + off) = hv;
        *(u16x8_t*)((char*)QsL + off) = lv;
    }

    for (int kt = 0; kt < 4; ++kt) {
        int j0 = kt * 64;
        __syncthreads();
        {
            int r = sr;
            int n = j0 + r;
            float v[8] = {0.f,0.f,0.f,0.f,0.f,0.f,0.f,0.f};
            if (n < NN) {
                float4 a0 = *(const float4*)(base + (size_t)n * 2304 + 768 + sq * 8);
                float4 a1 = *(const float4*)(base + (size_t)n * 2304 + 768 + sq * 8 + 4);
                v[0]=a0.x; v[1]=a0.y; v[2]=a0.z; v[3]=a0.w;
                v[4]=a1.x; v[5]=a1.y; v[6]=a1.z; v[7]=a1.w;
            }
            u16x8_t hv, lv;
            #pragma unroll
            for (int t = 0; t < 8; ++t) {
                unsigned short hh = f2bf(v[t]);
                hv[t] = hh; lv[t] = f2bf(v[t] - bf2f(hh));
            }
            int off = r * 128 + ((sq * 16) ^ ((r & 7) << 4));
            *(u16x8_t*)((char*)KsH + off) = hv;
            *(u16x8_t*)((char*)KsL + off) = lv;
        }
        __syncthreads();

        f32x4_t acc[2] = {};
        #pragma unroll
        for (int kk = 0; kk < 2; ++kk) {
            int colb = kk * 64 + colb_base;
            bf16x8_t qh[2], ql[2], kh, kl;
            #pragma unroll
            for (int i = 0; i < 2; ++i) {
                int ra = wm + i * 16 + lrow;
                int oa = ra * 128 + (colb ^ ((ra & 7) << 4));
                qh[i] = *(const bf16x8_t*)((const char*)QsH + oa);
                ql[i] = *(const bf16x8_t*)((const char*)QsL + oa);
            }
            int rb = wn + lrow;
            int ob = rb * 128 + (colb ^ ((rb & 7) << 4));
            kh = *(const bf16x8_t*)((const char*)KsH + ob);
            kl = *(const bf16x8_t*)((const char*)KsL + ob);
            #pragma unroll
            for (int mi = 0; mi < 2; ++mi) {
                acc[mi] = __builtin_amdgcn_mfma_f32_16x16x32_bf16(qh[mi], kh, acc[mi], 0, 0, 0);
                acc[mi] = __builtin_amdgcn_mfma_f32_16x16x32_bf16(qh[mi], kl, acc[mi], 0, 0, 0);
                acc[mi] = __builtin_amdgcn_mfma_f32_16x16x32_bf16(ql[mi], kh, acc[mi], 0, 0, 0);
            }
        }
        int jc = j0 + wn + lrow;
        if (jc < 224) {
            #pragma unroll
            for (int mi = 0; mi < 2; ++mi) {
                #pragma unroll
                for (int j = 0; j < 4; ++j) {
                    int row = wm + mi * 16 + lq * 4 + j;
                    int s = (row & 7) ^ (row >> 3);
                    *(float*)(psb + row * 896 + ((jc * 4) ^ (s << 4))) = acc[mi][j] * 0.125f;
                }
            }
        }
    }
    __syncthreads();

    {
        int i = tid >> 3, l = tid & 7;
        int s = (i & 7) ^ (i >> 3);
        char* prow = psb + i * 896;
        float mx = -1e30f;
        for (int j = l; j < NN; j += 8) mx = fmaxf(mx, *(const float*)(prow + ((j * 4) ^ (s << 4))));
        mx = fmaxf(mx, __shfl_xor(mx, 1, 8));
        mx = fmaxf(mx, __shfl_xor(mx, 2, 8));
        mx = fmaxf(mx, __shfl_xor(mx, 4, 8));
        float sum = 0.f;
        for (int j = l; j < NN; j += 8) {
            float* pp = (float*)(prow + ((j * 4) ^ (s << 4)));
            float e = expf(*pp - mx); *pp = e; sum += e;
        }
        sum += __shfl_xor(sum, 1, 8);
        sum += __shfl_xor(sum, 2, 8);
        sum += __shfl_xor(sum, 4, 8);
        float inv = 1.f / sum;
        for (int j = l; j < NN; j += 8) {
            float* pp = (float*)(prow + ((j * 4) ^ (s << 4)));
            *pp *= inv;
        }
    }

    f32x4_t oacc[2] = {};
    for (int kt = 0; kt < 4; ++kt) {
        int j0 = kt * 64;
        __syncthreads();
        {
            int r = sr;
            int n = j0 + r;
            float v[8] = {0.f,0.f,0.f,0.f,0.f,0.f,0.f,0.f};
            if (n < NN) {
                float4 a0 = *(const float4*)(base + (size_t)n * 2304 + 1536 + sq * 8);
                float4 a1 = *(const float4*)(base + (size_t)n * 2304 + 1536 + sq * 8 + 4);
                v[0]=a0.x; v[1]=a0.y; v[2]=a0.z; v[3]=a0.w;
                v[4]=a1.x; v[5]=a1.y; v[6]=a1.z; v[7]=a1.w;
            }
            #pragma unroll
            for (int t = 0; t < 8; ++t) {
                int d = sq * 8 + t;
                int sw = ((d & 7) ^ (d >> 3)) << 4;
                unsigned short hh = f2bf(v[t]);
                int off = d * 128 + ((r * 2) ^ sw);
                *(unsigned short*)((char*)KsH + off) = hh;
                *(unsigned short*)((char*)KsL + off) = f2bf(v[t] - bf2f(hh));
            }
        }
        __syncthreads();

        int kkmax = (kt == 3) ? 1 : 2;
        for (int kk = 0; kk < kkmax; ++kk) {
            int colb = kk * 64 + colb_base;
            bf16x8_t pah[2], pal[2], vh, vl;
            #pragma unroll
            for (int i = 0; i < 2; ++i) {
                int ra = wm + i * 16 + lrow;
                int s = (ra & 7) ^ (ra >> 3);
                const char* prow = psb + ra * 896;
                int jb = (j0 + kk * 32 + lq * 8) * 4;
                float4 a0 = *(const float4*)(prow + (jb ^ (s << 4)));
                float4 a1 = *(const float4*)(prow + ((jb + 16) ^ (s << 4)));
                float vv[8] = {a0.x,a0.y,a0.z,a0.w,a1.x,a1.y,a1.z,a1.w};
                u16x8_t hv, lv;
                #pragma unroll
                for (int t = 0; t < 8; ++t) {
                    unsigned short hh = f2bf(vv[t]);
                    hv[t] = hh; lv[t] = f2bf(vv[t] - bf2f(hh));
                }
                pah[i] = *(bf16x8_t*)&hv;
                pal[i] = *(bf16x8_t*)&lv;
            }
            int rb = wn + lrow;
            int ob = rb * 128 + (colb ^ (((rb & 7) ^ (rb >> 3)) << 4));
            vh = *(const bf16x8_t*)((const char*)KsH + ob);
            vl = *(const bf16x8_t*)((const char*)KsL + ob);
            #pragma unroll
            for (int mi = 0; mi < 2; ++mi) {
                oacc[mi] = __builtin_amdgcn_mfma_f32_16x16x32_bf16(pah[mi], vh, oacc[mi], 0, 0, 0);
                oacc[mi] = __builtin_amdgcn_mfma_f32_16x16x32_bf16(pah[mi], vl, oacc[mi], 0, 0, 0);
                oacc[mi] = __builtin_amdgcn_mfma_f32_16x16x32_bf16(pal[mi], vh, oacc[mi], 0, 0, 0);
            }
        }
    }

    #pragma unroll
    for (int mi = 0; mi < 2; ++mi) {
        int col = h * 64 + wn + lrow;
        #pragma unroll
        for (int j = 0; j < 4; ++j) {
            int n = q0 + wm + mi * 16 + lq * 4 + j;
            if (n < NN) {
                float v = oacc[mi][j];
                unsigned short hh = f2bf(v);
                size_t o = (size_t)(b * NN + n) * DIMC + col;
                ao_h[o] = hh;
                ao_l[o] = f2bf(v - bf2f(hh));
            }
        }
    }
}

__global__ void init_kernel(int* __restrict__ counts, int* __restrict__ row2tok, int cap,
                            unsigned short* __restrict__ zrow) {
    int i = blockIdx.x * blockDim.x + threadIdx.x;
    if (i < 8) counts[i] = 0;
    if (i < 128) zrow[i] = 0;
    if (i < cap) row2tok[i] = -1;
}

__global__ void offsets_kernel(const int* __restrict__ counts, int* __restrict__ offsets,
                               int* __restrict__ cursor) {
    if (threadIdx.x == 0 && blockIdx.x == 0) {
        int off = 0;
        for (int e = 0; e < 8; ++e) {
            offsets[e] = off;
            cursor[e]  = off;
            off += ((counts[e] + 63) / 64) * 64;  // pad each segment to BM=64
        }
        offsets[8] = off;
    }
}

__global__ void fill_kernel(const int* __restrict__ tok_e, int* __restrict__ cursor,
                            int* __restrict__ row2tok, int* __restrict__ tok_row) {
    int t = blockIdx.x * blockDim.x + threadIdx.x;
    if (t >= TT) return;
    #pragma unroll
    for (int k = 0; k < 2; ++k) {
        int e = tok_e[t*2+k];
        int slot = atomicAdd(&cursor[e], 1);
        row2tok[slot] = t;
        tok_row[t*2+k] = slot;
    }
}

// ---------------- transpose + hi/lo split: src [R][C] fp32 -> dh/dl [C][R] bf16 ----------------
__global__ void transpose_split_bf16(const float* __restrict__ src,
                                     unsigned short* __restrict__ dh,
                                     unsigned short* __restrict__ dl, int R, int C) {
    __shared__ float tile[64][65];
    int c0 = blockIdx.x * 64, r0 = blockIdx.y * 64;
    int tid = threadIdx.x;
    int tr = tid >> 4;
    int tc = (tid & 15) * 4;
    #pragma unroll
    for (int p = 0; p < 4; ++p) {
        int r = tr + p * 16;
        const float4 v = *(const float4*)(src + (size_t)(r0 + r) * C + c0 + tc);
        tile[r][tc+0] = v.x; tile[r][tc+1] = v.y; tile[r][tc+2] = v.z; tile[r][tc+3] = v.w;
    }
    __syncthreads();
    #pragma unroll
    for (int p = 0; p < 4; ++p) {
        int c = tr + p * 16;
        ushort4 h, l;
        float v0 = tile[tc+0][c], v1 = tile[tc+1][c], v2 = tile[tc+2][c], v3 = tile[tc+3][c];
        h.x = f2bf(v0); l.x = f2bf(v0 - bf2f(h.x));
        h.y = f2bf(v1); l.y = f2bf(v1 - bf2f(h.y));
        h.z = f2bf(v2); l.z = f2bf(v2 - bf2f(h.z));
        h.w = f2bf(v3); l.w = f2bf(v3 - bf2f(h.w));
        size_t off = (size_t)(c0 + c) * R + r0 + tc;
        *(ushort4*)(dh + off) = h;
        *(ushort4*)(dl + off) = l;
    }
}

// ---------------- split-precision MFMA GEMM, gl_lds staging + XCD remap ----------------
// 1D grid: L = npanel*nmb + mb (mb fastest -> consecutive blocks share B panel on one XCD).
template<int RES>
__global__ void mfma_gemm_split(const unsigned short* __restrict__ Ah,
                                const unsigned short* __restrict__ Al,
                                const unsigned short* __restrict__ Bth,
                                const unsigned short* __restrict__ Btl,
                                const float* __restrict__ bias,
                                const float* __restrict__ res,
                                float* __restrict__ C,
                                const unsigned short* __restrict__ zrow,
                                int M, int N, int K, int nmb) {
    __shared__ unsigned short AsH[64 * 64];
    __shared__ unsigned short AsL[64 * 64];
    __shared__ unsigned short BsH[64 * 64];
    __shared__ unsigned short BsL[64 * 64];

    int L = xcd_remap(blockIdx.x, gridDim.x);
    int m0 = (L % nmb) * 64;
    int n0 = (L / nmb) * 64;
    int tid = threadIdx.x;
    int lane = tid & 63;
    int wid = tid >> 6;
    int wm = (wid >> 1) * 32;
    int wn = (wid & 1) * 32;
    int colb_base = (lane >> 4) * 16;
    int lrow = lane & 15;

    f32x4_t acc[2][2] = {};

    for (int k0 = 0; k0 < K; k0 += 64) {
        #pragma unroll
        for (int p = 0; p < 2; ++p) {
            int s = tid + p * 256;         // slot 0..511
            int r = s >> 3, c = s & 7;
            int gc = c ^ (r & 7);          // pre-swizzled source chunk
            bool inM = (m0 + r < M);
            size_t aoff = (size_t)(m0 + r) * K + k0 + gc * 8;
            gl_lds16(inM ? (const void*)(Ah + aoff) : (const void*)zrow, (char*)AsH + s * 16);
            gl_lds16(inM ? (const void*)(Al + aoff) : (const void*)zrow, (char*)AsL + s * 16);
            size_t boff = (size_t)(n0 + r) * K + k0 + gc * 8;
            gl_lds16((const void*)(Bth + boff), (char*)BsH + s * 16);
            gl_lds16((const void*)(Btl + boff), (char*)BsL + s * 16);
        }
        __syncthreads();
        #pragma unroll
        for (int kk = 0; kk < 2; ++kk) {
            int colb = kk * 64 + colb_base;
            bf16x8_t ah[2], al[2], bh[2], bl[2];
            #pragma unroll
            for (int i = 0; i < 2; ++i) {
                int ra = wm + i * 16 + lrow;
                int oa = ra * 128 + (colb ^ ((ra & 7) << 4));
                ah[i] = *(const bf16x8_t*)((const char*)AsH + oa);
                al[i] = *(const bf16x8_t*)((const char*)AsL + oa);
                int rb = wn + i * 16 + lrow;
                int ob = rb * 128 + (colb ^ ((rb & 7) << 4));
                bh[i] = *(const bf16x8_t*)((const char*)BsH + ob);
                bl[i] = *(const bf16x8_t*)((const char*)BsL + ob);
            }
            #pragma unroll
            for (int mi = 0; mi < 2; ++mi)
                #pragma unroll
                for (int ni = 0; ni < 2; ++ni) {
                    acc[mi][ni] = __builtin_amdgcn_mfma_f32_16x16x32_bf16(
                        ah[mi], bh[ni], acc[mi][ni], 0, 0, 0);
                    acc[mi][ni] = __builtin_amdgcn_mfma_f32_16x16x32_bf16(
                        ah[mi], bl[ni], acc[mi][ni], 0, 0, 0);
                    acc[mi][ni] = __builtin_amdgcn_mfma_f32_16x16x32_bf16(
                        al[mi], bh[ni], acc[mi][ni], 0, 0, 0);
                }
        }
        __syncthreads();
    }

    #pragma unroll
    for (int mi = 0; mi < 2; ++mi) {
        #pragma unroll
        for (int ni = 0; ni < 2; ++ni) {
            int col = n0 + wn + ni * 16 + lrow;
            #pragma unroll
            for (int j = 0; j < 4; ++j) {
                int row = m0 + wm + mi * 16 + (lane >> 4) * 4 + j;
                if (row < M) {
                    float v = acc[mi][ni][j] + bias[col];
                    if (RES) v += res[(size_t)row * N + col];
                    C[(size_t)row * N + col] = v;
                }
            }
        }
    }
}

// ---------------- grouped bf16 MFMA GEMM, 64x128, direct fp32-weight B staging ----------------
// B read straight from w[e] fp32 [K][N]; convert+transpose into Bs[n][k] bf16 swizzled
// (attn V^T idiom). A side: gl_lds on bf16 activations. Read side unchanged (validated).
template<int GATHER, int GELU, int OUT_BF16>
__global__ void mfma_gemm_grouped(const unsigned short* __restrict__ A,
                                  const float* __restrict__ W,
                                  const float* __restrict__ bias,
                                  const int* __restrict__ offsets,
                                  const int* __restrict__ row2tok,
                                  void* __restrict__ Cout,
                                  const unsigned short* __restrict__ zrow,
                                  int N, int K, int nxb) {
    __shared__ unsigned short As[64 * 64];    // 8 KB
    __shared__ unsigned short Bs[128 * 64];   // 16 KB [n][k] swizzled
    __shared__ int toks[64];

    int L = xcd_remap(blockIdx.x, gridDim.x);
    int xb = L % nxb;
    int n0 = (L / nxb) * 128;
    int r0 = xb * 64;
    if (r0 >= offsets[8]) return;
    int e = 0;
    while (r0 >= offsets[e + 1]) ++e;

    int tid = threadIdx.x;
    if (GATHER && tid < 64) toks[tid] = row2tok[r0 + tid];
    __syncthreads();

    const float* We = W + (size_t)e * K * N;

    int lane = tid & 63;
    int wid = tid >> 6;
    int wm = (wid >> 1) * 32;
    int wn = (wid & 1) * 64;
    int colb_base = (lane >> 4) * 16;
    int lrow = lane & 15;

    f32x4_t acc[2][4] = {};

    for (int k0 = 0; k0 < K; k0 += 64) {
        // A: 512 slots via gl_lds (2/thread), source-chunk swizzled
        #pragma unroll
        for (int p = 0; p < 2; ++p) {
            int s = tid + p * 256;
            int r = s >> 3, c = s & 7;
            int gc = c ^ (r & 7);
            const void* asrc;
            if (GATHER) {
                int tok = toks[r];
                asrc = (tok >= 0) ? (const void*)(A + (size_t)tok * K + k0 + gc * 8)
                                  : (const void*)zrow;
            } else {
                asrc = (const void*)(A + (size_t)(r0 + r) * K + k0 + gc * 8);
            }
            gl_lds16(asrc, (char*)As + s * 16);
        }
        // B: fp32 [K][N] tile (64k x 128n) -> Bs[n][k] bf16; each idx: 2 k-rows x 8 n
        #pragma unroll
        for (int p = 0; p < 2; ++p) {
            int idx = tid + p * 256;       // 0..511
            int k2 = idx & 31;             // k = 2*k2
            int nc = idx >> 5;             // 0..15 -> 8-n chunk
            const float* w0 = We + (size_t)(k0 + 2 * k2) * N + n0 + nc * 8;
            float4 a0 = *(const float4*)(w0);
            float4 a1 = *(const float4*)(w0 + 4);
            float4 b0 = *(const float4*)(w0 + N);
            float4 b1 = *(const float4*)(w0 + N + 4);
            float ka[8] = {a0.x,a0.y,a0.z,a0.w,a1.x,a1.y,a1.z,a1.w};
            float kb[8] = {b0.x,b0.y,b0.z,b0.w,b1.x,b1.y,b1.z,b1.w};
            #pragma unroll
            for (int i = 0; i < 8; ++i) {
                int n = nc * 8 + i;
                unsigned int pk = (unsigned int)f2bf(ka[i]) |
                                  ((unsigned int)f2bf(kb[i]) << 16);
                *(unsigned int*)((char*)Bs + n * 128 + ((k2 * 4) ^ ((n & 7) << 4))) = pk;
            }
        }
        __syncthreads();
        #pragma unroll
        for (int kk = 0; kk < 2; ++kk) {
            int colb = kk * 64 + colb_base;
            bf16x8_t a[2], b[4];
            #pragma unroll
            for (int i = 0; i < 2; ++i) {
                int ra = wm + i * 16 + lrow;
                a[i] = *(const bf16x8_t*)((const char*)As + ra * 128 + (colb ^ ((ra & 7) << 4)));
            }
            #pragma unroll
            for (int i = 0; i < 4; ++i) {
                int rb = wn + i * 16 + lrow;
                b[i] = *(const bf16x8_t*)((const char*)Bs + rb * 128 + (colb ^ ((rb & 7) << 4)));
            }
            #pragma unroll
            for (int mi = 0; mi < 2; ++mi)
                #pragma unroll
                for (int ni = 0; ni < 4; ++ni)
                    acc[mi][ni] = __builtin_amdgcn_mfma_f32_16x16x32_bf16(
                        a[mi], b[ni], acc[mi][ni], 0, 0, 0);
        }
        __syncthreads();
    }

    #pragma unroll
    for (int mi = 0; mi < 2; ++mi) {
        #pragma unroll
        for (int ni = 0; ni < 4; ++ni) {
            int col = n0 + wn + ni * 16 + lrow;
            float bv = GELU ? bias[(size_t)e * N + col] : 0.f;
            #pragma unroll
            for (int j = 0; j < 4; ++j) {
                int row = r0 + wm + mi * 16 + (lane >> 4) * 4 + j;
                float v = acc[mi][ni][j] + bv;
                if (GELU) v = 0.5f * v * (1.f + erff(v * 0.70710678f));
                if (OUT_BF16)
                    ((unsigned short*)Cout)[(size_t)row * N + col] = f2bf(v);
                else
                    ((float*)Cout)[(size_t)row * N + col] = v;
            }
        }
    }
}

// ---------------- combine: out = x_res + sum_k g_k*(y[row_k] + b2[e_k]) ----------------
__global__ void combine_kernel(const float* __restrict__ x_res, const float* __restrict__ y,
                               const float* __restrict__ b2, const int* __restrict__ tok_e,
                               const float* __restrict__ tok_g, const int* __restrict__ tok_row,
                               float* __restrict__ out) {
    int t = blockIdx.x;
    int c = blockIdx.y * 256 + threadIdx.x;
    int e0 = tok_e[t*2], e1 = tok_e[t*2+1];
    float g0 = tok_g[t*2], g1 = tok_g[t*2+1];
    int r0 = tok_row[t*2], r1 = tok_row[t*2+1];
    float v = x_res[(size_t)t * DIMC + c]
            + g0 * (y[(size_t)r0 * DIMC + c] + b2[(size_t)e0 * DIMC + c])
            + g1 * (y[(size_t)r1 * DIMC + c] + b2[(size_t)e1 * DIMC + c]);
    out[(size_t)t * DIMC + c] = v;
}

extern "C" void kernel_launch(void* const* d_in, const int* in_sizes, int n_in,
                              void* d_out, int out_size, void* d_ws, size_t ws_size,
                              hipStream_t stream) {
    const float* x      = (const float*)d_in[0];
    const float* ln1_g  = (const float*)d_in[1];
    const float* ln1_b  = (const float*)d_in[2];
    const float* qkv_w  = (const float*)d_in[3];
    const float* qkv_b  = (const float*)d_in[4];
    const float* proj_w = (const float*)d_in[5];
    const float* proj_b = (const float*)d_in[6];
    const float* ln2_g  = (const float*)d_in[7];
    const float* ln2_b  = (const float*)d_in[8];
    const float* gate_w = (const float*)d_in[9];
    const float* w1     = (const float*)d_in[10];
    const float* b1     = (const float*)d_in[11];
    const float* w2     = (const float*)d_in[12];
    const float* b2     = (const float*)d_in[13];
    float* out = (float*)d_out;

    char* p = (char*)d_ws;
    auto alloc = [&](size_t nbytes) {
        void* r = (void*)p;
        p += (nbytes + 255) & ~(size_t)255;
        return r;
    };
    unsigned short* xn1_h   = (unsigned short*)alloc((size_t)TT * DIMC * 2);
    unsigned short* xn1_l   = (unsigned short*)alloc((size_t)TT * DIMC * 2);
    float*          qkv     = (float*)alloc((size_t)TT * 2304 * 4);
    unsigned short* ao_h    = (unsigned short*)alloc((size_t)TT * DIMC * 2);
    unsigned short* ao_l    = (unsigned short*)alloc((size_t)TT * DIMC * 2);
    float*          x_res   = (float*)alloc((size_t)TT * DIMC * 4);
    unsigned short* xn2_bf  = (unsigned short*)alloc((size_t)TT * DIMC * 2);
    unsigned short* h       = (unsigned short*)alloc((size_t)CAP_ROWS * HID * 2);
    float*          y       = (float*)alloc((size_t)CAP_ROWS * DIMC * 4);
    unsigned short* qwt_h   = (unsigned short*)alloc((size_t)DIMC * 2304 * 2);
    unsigned short* qwt_l   = (unsigned short*)alloc((size_t)DIMC * 2304 * 2);
    unsigned short* pwt_h   = (unsigned short*)alloc((size_t)DIMC * DIMC * 2);
    unsigned short* pwt_l   = (unsigned short*)alloc((size_t)DIMC * DIMC * 2);
    float*          tok_g   = (float*)alloc((size_t)2 * TT * 4);
    int*            tok_e   = (int*)alloc((size_t)2 * TT * 4);
    int*            tok_row = (int*)alloc((size_t)2 * TT * 4);
    int*            row2tok = (int*)alloc((size_t)CAP_ROWS * 4);
    unsigned short* zrow    = (unsigned short*)alloc(256);
    int*            counts  = (int*)alloc(32 * 4);
    int*            offsets = (int*)alloc(32 * 4);
    int*            cursor  = (int*)alloc(32 * 4);

    init_kernel<<<(CAP_ROWS + 255) / 256, 256, 0, stream>>>(counts, row2tok, CAP_ROWS, zrow);

    // activation-weight transposes for qkv/proj (small); experts read w1/w2 directly
    transpose_split_bf16<<<dim3(2304 / 64, DIMC / 64), 256, 0, stream>>>(qkv_w, qwt_h, qwt_l,
                                                                         DIMC, 2304);
    transpose_split_bf16<<<dim3(DIMC / 64, DIMC / 64), 256, 0, stream>>>(proj_w, pwt_h, pwt_l,
                                                                         DIMC, DIMC);

    ln_kernel_t<0><<<TT, 256, 0, stream>>>(x, ln1_g, ln1_b, xn1_h, xn1_l,
                                           nullptr, nullptr, nullptr, nullptr);

    {
        int nmb = (TT + 63) / 64;                       // 25
        int nwg = nmb * (2304 / 64);                    // 900
        mfma_gemm_split<0><<<nwg, 256, 0, stream>>>(
            xn1_h, xn1_l, qwt_h, qwt_l, qkv_b, nullptr, qkv, zrow, TT, 2304, DIMC, nmb);
    }

    attn_mfma_kernel<<<dim3(BB * HEADS, 4), 512, 0, stream>>>(qkv, ao_h, ao_l);

    {
        int nmb = (TT + 63) / 64;                       // 25
        int nwg = nmb * (DIMC / 64);                    // 300
        mfma_gemm_split<1><<<nwg, 256, 0, stream>>>(
            ao_h, ao_l, pwt_h, pwt_l, proj_b, x, x_res, zrow, TT, DIMC, DIMC, nmb);
    }

    // ln2 with fused gate (logits in fp32, top-2 + softmax + counts)
    ln_kernel_t<1><<<TT, 256, 0, stream>>>(x_res, ln2_g, ln2_b, xn2_bf, nullptr,
                                           gate_w, tok_e, tok_g, counts);

    offsets_kernel<<<1, 64, 0, stream>>>(counts, offsets, cursor);

    fill_kernel<<<(TT + 255) / 256, 256, 0, stream>>>(tok_e, cursor, row2tok, tok_row);

    {
        int nxb = CAP_ROWS / 64;                        // 66
        int nwg1 = (HID / 128) * nxb;                   // 24*66 = 1584
        mfma_gemm_grouped<1, 1, 1><<<nwg1, 256, 0, stream>>>(
            xn2_bf, w1, b1, offsets, row2tok, h, zrow, HID, DIMC, nxb);

        int nwg2 = (DIMC / 128) * nxb;                  // 6*66 = 396
        mfma_gemm_grouped<0, 0, 0><<<nwg2, 256, 0, stream>>>(
            h, w2, nullptr, offsets, row2tok, y, zrow, DIMC, HID, nxb);
    }

    combine_kernel<<<dim3(TT, 3), 256, 0, stream>>>(x_res, y, b2, tok_e, tok_g, tok_row, out);
}

// Round 16
// 277.108 us; speedup vs baseline: 1.3621x; 1.3621x over previous
//
#include <hip/hip_runtime.h>
#include <hip/hip_bf16.h>
#include <math.h>

#define DIMC 768
#define HEADS 12
#define HD 64
#define EXPERTS 8
#define HID 3072
#define BB 8
#define NN 196
#define TT (BB*NN)      // 1568
#define CAP_ROWS 4224   // multiple of 64, >= 2*TT + 8*64 headroom
#define LN_EPS 1e-5f

typedef float f32x4_t __attribute__((ext_vector_type(4)));
typedef short bf16x8_t __attribute__((ext_vector_type(8)));
typedef unsigned short u16x8_t __attribute__((ext_vector_type(8)));

__device__ __forceinline__ unsigned short f2bf(float f) {
    unsigned int u = __float_as_uint(f);
    u += 0x7FFFu + ((u >> 16) & 1u);   // round-to-nearest-even
    return (unsigned short)(u >> 16);
}
__device__ __forceinline__ float bf2f(unsigned short u) {
    return __uint_as_float(((unsigned int)u) << 16);
}

// async global->LDS, 16B per lane; LDS dest = wave-uniform base + lane*16 (linear)
__device__ __forceinline__ void gl_lds16(const void* g, void* l) {
    __builtin_amdgcn_global_load_lds(
        (const __attribute__((address_space(1))) unsigned int*)g,
        (__attribute__((address_space(3))) unsigned int*)l, 16, 0, 0);
}

// bijective XCD-chunked remap (m204): physical bid -> logical L
__device__ __forceinline__ int xcd_remap(int pbid, int nwg) {
    int q = nwg >> 3, r8 = nwg & 7;
    int xcd = pbid & 7, slot = pbid >> 3;
    return (xcd < r8) ? xcd * (q + 1) + slot
                      : r8 * (q + 1) + (xcd - r8) * q + slot;
}

// ---------------- LayerNorm (+ optional fused gate): one block per token, 256 threads ----------------
template<int GATE>
__global__ void ln_kernel_t(const float* __restrict__ x, const float* __restrict__ g,
                            const float* __restrict__ b,
                            unsigned short* __restrict__ out_hi,
                            unsigned short* __restrict__ out_lo,
                            const float* __restrict__ gw, int* __restrict__ tok_e,
                            float* __restrict__ tok_g, int* __restrict__ counts) {
    int t = blockIdx.x;
    const float* xr = x + (size_t)t * DIMC;
    int tid = threadIdx.x;
    float v0 = xr[tid], v1 = xr[tid + 256], v2 = xr[tid + 512];
    __shared__ float red[256];
    red[tid] = v0 + v1 + v2;
    __syncthreads();
    for (int off = 128; off > 0; off >>= 1) {
        if (tid < off) red[tid] += red[tid + off];
        __syncthreads();
    }
    float mu = red[0] * (1.0f / DIMC);
    __syncthreads();
    float d0 = v0 - mu, d1 = v1 - mu, d2 = v2 - mu;
    red[tid] = d0*d0 + d1*d1 + d2*d2;
    __syncthreads();
    for (int off = 128; off > 0; off >>= 1) {
        if (tid < off) red[tid] += red[tid + off];
        __syncthreads();
    }
    float rstd = rsqrtf(red[0] * (1.0f / DIMC) + LN_EPS);
    float o0 = d0 * rstd * g[tid]       + b[tid];
    float o1 = d1 * rstd * g[tid + 256] + b[tid + 256];
    float o2 = d2 * rstd * g[tid + 512] + b[tid + 512];
    {
        unsigned short* o = out_hi + (size_t)t * DIMC;
        unsigned short h0 = f2bf(o0), h1 = f2bf(o1), h2 = f2bf(o2);
        o[tid] = h0; o[tid + 256] = h1; o[tid + 512] = h2;
        if (out_lo) {
            unsigned short* ol = out_lo + (size_t)t * DIMC;
            ol[tid]       = f2bf(o0 - bf2f(h0));
            ol[tid + 256] = f2bf(o1 - bf2f(h1));
            ol[tid + 512] = f2bf(o2 - bf2f(h2));
        }
    }
    if (GATE) {
        float p[8];
        const float* g0r = gw + (size_t)tid * 8;
        const float* g1r = gw + ((size_t)tid + 256) * 8;
        const float* g2r = gw + ((size_t)tid + 512) * 8;
        #pragma unroll
        for (int e = 0; e < 8; ++e)
            p[e] = o0 * g0r[e] + o1 * g1r[e] + o2 * g2r[e];
        #pragma unroll
        for (int off = 32; off > 0; off >>= 1)
            #pragma unroll
            for (int e = 0; e < 8; ++e) p[e] += __shfl_xor(p[e], off, 64);
        __shared__ float redw[4][8];
        int lane = tid & 63, w = tid >> 6;
        if (lane == 0) {
            #pragma unroll
            for (int e = 0; e < 8; ++e) redw[w][e] = p[e];
        }
        __syncthreads();
        if (tid == 0) {
            float lg[8];
            #pragma unroll
            for (int e = 0; e < 8; ++e)
                lg[e] = redw[0][e] + redw[1][e] + redw[2][e] + redw[3][e];
            int e0 = 0; float l0 = lg[0];
            #pragma unroll
            for (int e = 1; e < 8; ++e) if (lg[e] > l0) { l0 = lg[e]; e0 = e; }
            int e1 = -1; float l1 = -3e38f;
            #pragma unroll
            for (int e = 0; e < 8; ++e) if (e != e0 && lg[e] > l1) { l1 = lg[e]; e1 = e; }
            float pp = expf(l1 - l0);
            float ga = 1.f / (1.f + pp);
            float gb = pp / (1.f + pp);
            tok_e[t*2] = e0; tok_e[t*2+1] = e1;
            tok_g[t*2] = ga; tok_g[t*2+1] = gb;
            atomicAdd(&counts[e0], 1);
            atomicAdd(&counts[e1], 1);
        }
    }
}

// ---------------- MFMA attention, split-precision, 512 threads / 8 waves (validated r11) ----------------
__global__ void attn_mfma_kernel(const float* __restrict__ qkv,
                                 unsigned short* __restrict__ ao_h,
                                 unsigned short* __restrict__ ao_l) {
    __shared__ char psb[64 * 896];                         // 56 KB, swizzled fp32 [64][224]
    __shared__ unsigned short QsH[64 * 64], QsL[64 * 64];
    __shared__ unsigned short KsH[64 * 64], KsL[64 * 64];

    int bh = blockIdx.x;
    int b = bh / HEADS, h = bh % HEADS;
    int q0 = blockIdx.y * 64;
    const float* base = qkv + (size_t)b * NN * 2304 + h * 64;

    int tid = threadIdx.x;                 // 0..511
    int sr = tid >> 3, sq = tid & 7;
    int lane = tid & 63;
    int wid = tid >> 6;
    int wm = (wid >> 2) * 32;
    int wn = (wid & 3) * 16;
    int lrow = lane & 15;
    int lq = lane >> 4;
    int colb_base = lq * 16;

    {
        int r = sr;
        int n = q0 + r;
        float v[8] = {0.f,0.f,0.f,0.f,0.f,0.f,0.f,0.f};
        if (n < NN) {
            float4 a0 = *(const float4*)(base + (size_t)n * 2304 + sq * 8);
            float4 a1 = *(const float4*)(base + (size_t)n * 2304 + sq * 8 + 4);
            v[0]=a0.x; v[1]=a0.y; v[2]=a0.z; v[3]=a0.w;
            v[4]=a1.x; v[5]=a1.y; v[6]=a1.z; v[7]=a1.w;
        }
        u16x8_t hv, lv;
        #pragma unroll
        for (int t = 0; t < 8; ++t) {
            unsigned short hh = f2bf(v[t]);
            hv[t] = hh; lv[t] = f2bf(v[t] - bf2f(hh));
        }
        int off = r * 128 + ((sq * 16) ^ ((r & 7) << 4));
        *(u16x8_t*)((char*)QsH + off) = hv;
        *(u16x8_t*)((char*)QsL + off) = lv;
    }

    for (int kt = 0; kt < 4; ++kt) {
        int j0 = kt * 64;
        __syncthreads();
        {
            int r = sr;
            int n = j0 + r;
            float v[8] = {0.f,0.f,0.f,0.f,0.f,0.f,0.f,0.f};
            if (n < NN) {
                float4 a0 = *(const float4*)(base + (size_t)n * 2304 + 768 + sq * 8);
                float4 a1 = *(const float4*)(base + (size_t)n * 2304 + 768 + sq * 8 + 4);
                v[0]=a0.x; v[1]=a0.y; v[2]=a0.z; v[3]=a0.w;
                v[4]=a1.x; v[5]=a1.y; v[6]=a1.z; v[7]=a1.w;
            }
            u16x8_t hv, lv;
            #pragma unroll
            for (int t = 0; t < 8; ++t) {
                unsigned short hh = f2bf(v[t]);
                hv[t] = hh; lv[t] = f2bf(v[t] - bf2f(hh));
            }
            int off = r * 128 + ((sq * 16) ^ ((r & 7) << 4));
            *(u16x8_t*)((char*)KsH + off) = hv;
            *(u16x8_t*)((char*)KsL + off) = lv;
        }
        __syncthreads();

        f32x4_t acc[2] = {};
        #pragma unroll
        for (int kk = 0; kk < 2; ++kk) {
            int colb = kk * 64 + colb_base;
            bf16x8_t qh[2], ql[2], kh, kl;
            #pragma unroll
            for (int i = 0; i < 2; ++i) {
                int ra = wm + i * 16 + lrow;
                int oa = ra * 128 + (colb ^ ((ra & 7) << 4));
                qh[i] = *(const bf16x8_t*)((const char*)QsH + oa);
                ql[i] = *(const bf16x8_t*)((const char*)QsL + oa);
            }
            int rb = wn + lrow;
            int ob = rb * 128 + (colb ^ ((rb & 7) << 4));
            kh = *(const bf16x8_t*)((const char*)KsH + ob);
            kl = *(const bf16x8_t*)((const char*)KsL + ob);
            #pragma unroll
            for (int mi = 0; mi < 2; ++mi) {
                acc[mi] = __builtin_amdgcn_mfma_f32_16x16x32_bf16(qh[mi], kh, acc[mi], 0, 0, 0);
                acc[mi] = __builtin_amdgcn_mfma_f32_16x16x32_bf16(qh[mi], kl, acc[mi], 0, 0, 0);
                acc[mi] = __builtin_amdgcn_mfma_f32_16x16x32_bf16(ql[mi], kh, acc[mi], 0, 0, 0);
            }
        }
        int jc = j0 + wn + lrow;
        if (jc < 224) {
            #pragma unroll
            for (int mi = 0; mi < 2; ++mi) {
                #pragma unroll
                for (int j = 0; j < 4; ++j) {
                    int row = wm + mi * 16 + lq * 4 + j;
                    int s = (row & 7) ^ (row >> 3);
                    *(float*)(psb + row * 896 + ((jc * 4) ^ (s << 4))) = acc[mi][j] * 0.125f;
                }
            }
        }
    }
    __syncthreads();

    {
        int i = tid >> 3, l = tid & 7;
        int s = (i & 7) ^ (i >> 3);
        char* prow = psb + i * 896;
        float mx = -1e30f;
        for (int j = l; j < NN; j += 8) mx = fmaxf(mx, *(const float*)(prow + ((j * 4) ^ (s << 4))));
        mx = fmaxf(mx, __shfl_xor(mx, 1, 8));
        mx = fmaxf(mx, __shfl_xor(mx, 2, 8));
        mx = fmaxf(mx, __shfl_xor(mx, 4, 8));
        float sum = 0.f;
        for (int j = l; j < NN; j += 8) {
            float* pp = (float*)(prow + ((j * 4) ^ (s << 4)));
            float e = expf(*pp - mx); *pp = e; sum += e;
        }
        sum += __shfl_xor(sum, 1, 8);
        sum += __shfl_xor(sum, 2, 8);
        sum += __shfl_xor(sum, 4, 8);
        float inv = 1.f / sum;
        for (int j = l; j < NN; j += 8) {
            float* pp = (float*)(prow + ((j * 4) ^ (s << 4)));
            *pp *= inv;
        }
    }

    f32x4_t oacc[2] = {};
    for (int kt = 0; kt < 4; ++kt) {
        int j0 = kt * 64;
        __syncthreads();
        {
            int r = sr;
            int n = j0 + r;
            float v[8] = {0.f,0.f,0.f,0.f,0.f,0.f,0.f,0.f};
            if (n < NN) {
                float4 a0 = *(const float4*)(base + (size_t)n * 2304 + 1536 + sq * 8);
                float4 a1 = *(const float4*)(base + (size_t)n * 2304 + 1536 + sq * 8 + 4);
                v[0]=a0.x; v[1]=a0.y; v[2]=a0.z; v[3]=a0.w;
                v[4]=a1.x; v[5]=a1.y; v[6]=a1.z; v[7]=a1.w;
            }
            #pragma unroll
            for (int t = 0; t < 8; ++t) {
                int d = sq * 8 + t;
                int sw = ((d & 7) ^ (d >> 3)) << 4;
                unsigned short hh = f2bf(v[t]);
                int off = d * 128 + ((r * 2) ^ sw);
                *(unsigned short*)((char*)KsH + off) = hh;
                *(unsigned short*)((char*)KsL + off) = f2bf(v[t] - bf2f(hh));
            }
        }
        __syncthreads();

        int kkmax = (kt == 3) ? 1 : 2;
        for (int kk = 0; kk < kkmax; ++kk) {
            int colb = kk * 64 + colb_base;
            bf16x8_t pah[2], pal[2], vh, vl;
            #pragma unroll
            for (int i = 0; i < 2; ++i) {
                int ra = wm + i * 16 + lrow;
                int s = (ra & 7) ^ (ra >> 3);
                const char* prow = psb + ra * 896;
                int jb = (j0 + kk * 32 + lq * 8) * 4;
                float4 a0 = *(const float4*)(prow + (jb ^ (s << 4)));
                float4 a1 = *(const float4*)(prow + ((jb + 16) ^ (s << 4)));
                float vv[8] = {a0.x,a0.y,a0.z,a0.w,a1.x,a1.y,a1.z,a1.w};
                u16x8_t hv, lv;
                #pragma unroll
                for (int t = 0; t < 8; ++t) {
                    unsigned short hh = f2bf(vv[t]);
                    hv[t] = hh; lv[t] = f2bf(vv[t] - bf2f(hh));
                }
                pah[i] = *(bf16x8_t*)&hv;
                pal[i] = *(bf16x8_t*)&lv;
            }
            int rb = wn + lrow;
            int ob = rb * 128 + (colb ^ (((rb & 7) ^ (rb >> 3)) << 4));
            vh = *(const bf16x8_t*)((const char*)KsH + ob);
            vl = *(const bf16x8_t*)((const char*)KsL + ob);
            #pragma unroll
            for (int mi = 0; mi < 2; ++mi) {
                oacc[mi] = __builtin_amdgcn_mfma_f32_16x16x32_bf16(pah[mi], vh, oacc[mi], 0, 0, 0);
                oacc[mi] = __builtin_amdgcn_mfma_f32_16x16x32_bf16(pah[mi], vl, oacc[mi], 0, 0, 0);
                oacc[mi] = __builtin_amdgcn_mfma_f32_16x16x32_bf16(pal[mi], vh, oacc[mi], 0, 0, 0);
            }
        }
    }

    #pragma unroll
    for (int mi = 0; mi < 2; ++mi) {
        int col = h * 64 + wn + lrow;
        #pragma unroll
        for (int j = 0; j < 4; ++j) {
            int n = q0 + wm + mi * 16 + lq * 4 + j;
            if (n < NN) {
                float v = oacc[mi][j];
                unsigned short hh = f2bf(v);
                size_t o = (size_t)(b * NN + n) * DIMC + col;
                ao_h[o] = hh;
                ao_l[o] = f2bf(v - bf2f(hh));
            }
        }
    }
}

__global__ void init_kernel(int* __restrict__ counts, int* __restrict__ row2tok, int cap,
                            unsigned short* __restrict__ zrow) {
    int i = blockIdx.x * blockDim.x + threadIdx.x;
    if (i < 8) counts[i] = 0;
    if (i < 128) zrow[i] = 0;
    if (i < cap) row2tok[i] = -1;
}

__global__ void offsets_kernel(const int* __restrict__ counts, int* __restrict__ offsets,
                               int* __restrict__ cursor) {
    if (threadIdx.x == 0 && blockIdx.x == 0) {
        int off = 0;
        for (int e = 0; e < 8; ++e) {
            offsets[e] = off;
            cursor[e]  = off;
            off += ((counts[e] + 63) / 64) * 64;  // pad each segment to BM=64
        }
        offsets[8] = off;
    }
}

__global__ void fill_kernel(const int* __restrict__ tok_e, int* __restrict__ cursor,
                            int* __restrict__ row2tok, int* __restrict__ tok_row) {
    int t = blockIdx.x * blockDim.x + threadIdx.x;
    if (t >= TT) return;
    #pragma unroll
    for (int k = 0; k < 2; ++k) {
        int e = tok_e[t*2+k];
        int slot = atomicAdd(&cursor[e], 1);
        row2tok[slot] = t;
        tok_row[t*2+k] = slot;
    }
}

// ---------------- batched transpose + fp32->bf16: src [B][R][C] -> dst [B][C][R] ----------------
__global__ void transpose_bf16(const float* __restrict__ src, unsigned short* __restrict__ dst,
                               int R, int C) {
    __shared__ float tile[64][65];
    const float* s = src + (size_t)blockIdx.z * R * C;
    unsigned short* d = dst + (size_t)blockIdx.z * R * C;
    int c0 = blockIdx.x * 64, r0 = blockIdx.y * 64;
    int tid = threadIdx.x;
    int tr = tid >> 4;
    int tc = (tid & 15) * 4;
    #pragma unroll
    for (int p = 0; p < 4; ++p) {
        int r = tr + p * 16;
        const float4 v = *(const float4*)(s + (size_t)(r0 + r) * C + c0 + tc);
        tile[r][tc+0] = v.x; tile[r][tc+1] = v.y; tile[r][tc+2] = v.z; tile[r][tc+3] = v.w;
    }
    __syncthreads();
    #pragma unroll
    for (int p = 0; p < 4; ++p) {
        int c = tr + p * 16;
        ushort4 o;
        o.x = f2bf(tile[tc+0][c]);
        o.y = f2bf(tile[tc+1][c]);
        o.z = f2bf(tile[tc+2][c]);
        o.w = f2bf(tile[tc+3][c]);
        *(ushort4*)(d + (size_t)(c0 + c) * R + r0 + tc) = o;
    }
}

// ---------------- transpose + hi/lo split: src [R][C] fp32 -> dh/dl [C][R] bf16 ----------------
__global__ void transpose_split_bf16(const float* __restrict__ src,
                                     unsigned short* __restrict__ dh,
                                     unsigned short* __restrict__ dl, int R, int C) {
    __shared__ float tile[64][65];
    int c0 = blockIdx.x * 64, r0 = blockIdx.y * 64;
    int tid = threadIdx.x;
    int tr = tid >> 4;
    int tc = (tid & 15) * 4;
    #pragma unroll
    for (int p = 0; p < 4; ++p) {
        int r = tr + p * 16;
        const float4 v = *(const float4*)(src + (size_t)(r0 + r) * C + c0 + tc);
        tile[r][tc+0] = v.x; tile[r][tc+1] = v.y; tile[r][tc+2] = v.z; tile[r][tc+3] = v.w;
    }
    __syncthreads();
    #pragma unroll
    for (int p = 0; p < 4; ++p) {
        int c = tr + p * 16;
        ushort4 h, l;
        float v0 = tile[tc+0][c], v1 = tile[tc+1][c], v2 = tile[tc+2][c], v3 = tile[tc+3][c];
        h.x = f2bf(v0); l.x = f2bf(v0 - bf2f(h.x));
        h.y = f2bf(v1); l.y = f2bf(v1 - bf2f(h.y));
        h.z = f2bf(v2); l.z = f2bf(v2 - bf2f(h.z));
        h.w = f2bf(v3); l.w = f2bf(v3 - bf2f(h.w));
        size_t off = (size_t)(c0 + c) * R + r0 + tc;
        *(ushort4*)(dh + off) = h;
        *(ushort4*)(dl + off) = l;
    }
}

// ---------------- split-precision MFMA GEMM, gl_lds staging + XCD remap (r15 form) ----------------
template<int RES>
__global__ void mfma_gemm_split(const unsigned short* __restrict__ Ah,
                                const unsigned short* __restrict__ Al,
                                const unsigned short* __restrict__ Bth,
                                const unsigned short* __restrict__ Btl,
                                const float* __restrict__ bias,
                                const float* __restrict__ res,
                                float* __restrict__ C,
                                const unsigned short* __restrict__ zrow,
                                int M, int N, int K, int nmb) {
    __shared__ unsigned short AsH[64 * 64];
    __shared__ unsigned short AsL[64 * 64];
    __shared__ unsigned short BsH[64 * 64];
    __shared__ unsigned short BsL[64 * 64];

    int L = xcd_remap(blockIdx.x, gridDim.x);
    int m0 = (L % nmb) * 64;
    int n0 = (L / nmb) * 64;
    int tid = threadIdx.x;
    int lane = tid & 63;
    int wid = tid >> 6;
    int wm = (wid >> 1) * 32;
    int wn = (wid & 1) * 32;
    int colb_base = (lane >> 4) * 16;
    int lrow = lane & 15;

    f32x4_t acc[2][2] = {};

    for (int k0 = 0; k0 < K; k0 += 64) {
        #pragma unroll
        for (int p = 0; p < 2; ++p) {
            int s = tid + p * 256;         // slot 0..511
            int r = s >> 3, c = s & 7;
            int gc = c ^ (r & 7);          // pre-swizzled source chunk
            bool inM = (m0 + r < M);
            size_t aoff = (size_t)(m0 + r) * K + k0 + gc * 8;
            gl_lds16(inM ? (const void*)(Ah + aoff) : (const void*)zrow, (char*)AsH + s * 16);
            gl_lds16(inM ? (const void*)(Al + aoff) : (const void*)zrow, (char*)AsL + s * 16);
            size_t boff = (size_t)(n0 + r) * K + k0 + gc * 8;
            gl_lds16((const void*)(Bth + boff), (char*)BsH + s * 16);
            gl_lds16((const void*)(Btl + boff), (char*)BsL + s * 16);
        }
        __syncthreads();
        #pragma unroll
        for (int kk = 0; kk < 2; ++kk) {
            int colb = kk * 64 + colb_base;
            bf16x8_t ah[2], al[2], bh[2], bl[2];
            #pragma unroll
            for (int i = 0; i < 2; ++i) {
                int ra = wm + i * 16 + lrow;
                int oa = ra * 128 + (colb ^ ((ra & 7) << 4));
                ah[i] = *(const bf16x8_t*)((const char*)AsH + oa);
                al[i] = *(const bf16x8_t*)((const char*)AsL + oa);
                int rb = wn + i * 16 + lrow;
                int ob = rb * 128 + (colb ^ ((rb & 7) << 4));
                bh[i] = *(const bf16x8_t*)((const char*)BsH + ob);
                bl[i] = *(const bf16x8_t*)((const char*)BsL + ob);
            }
            #pragma unroll
            for (int mi = 0; mi < 2; ++mi)
                #pragma unroll
                for (int ni = 0; ni < 2; ++ni) {
                    acc[mi][ni] = __builtin_amdgcn_mfma_f32_16x16x32_bf16(
                        ah[mi], bh[ni], acc[mi][ni], 0, 0, 0);
                    acc[mi][ni] = __builtin_amdgcn_mfma_f32_16x16x32_bf16(
                        ah[mi], bl[ni], acc[mi][ni], 0, 0, 0);
                    acc[mi][ni] = __builtin_amdgcn_mfma_f32_16x16x32_bf16(
                        al[mi], bh[ni], acc[mi][ni], 0, 0, 0);
                }
        }
        __syncthreads();
    }

    #pragma unroll
    for (int mi = 0; mi < 2; ++mi) {
        #pragma unroll
        for (int ni = 0; ni < 2; ++ni) {
            int col = n0 + wn + ni * 16 + lrow;
            #pragma unroll
            for (int j = 0; j < 4; ++j) {
                int row = m0 + wm + mi * 16 + (lane >> 4) * 4 + j;
                if (row < M) {
                    float v = acc[mi][ni][j] + bias[col];
                    if (RES) v += res[(size_t)row * N + col];
                    C[(size_t)row * N + col] = v;
                }
            }
        }
    }
}

// ---------------- grouped bf16 MFMA GEMM, 64x128 (r14 form) + double-buffered 2-phase ----------------
// T3 minimum recipe: stage(next, buf^1) BEFORE compute(buf); ONE barrier per K-step.
template<int GATHER, int GELU, int OUT_BF16>
__global__ void mfma_gemm_grouped(const unsigned short* __restrict__ A,
                                  const unsigned short* __restrict__ Bt,
                                  const float* __restrict__ bias,
                                  const int* __restrict__ offsets,
                                  const int* __restrict__ row2tok,
                                  void* __restrict__ Cout,
                                  const unsigned short* __restrict__ zrow,
                                  int N, int K, int nxb) {
    __shared__ unsigned short As[2][64 * 64];    // 16 KB
    __shared__ unsigned short Bs[2][128 * 64];   // 32 KB
    __shared__ int toks[64];

    int L = xcd_remap(blockIdx.x, gridDim.x);
    int xb = L % nxb;
    int n0 = (L / nxb) * 128;
    int r0 = xb * 64;
    if (r0 >= offsets[8]) return;
    int e = 0;
    while (r0 >= offsets[e + 1]) ++e;

    int tid = threadIdx.x;
    if (GATHER && tid < 64) toks[tid] = row2tok[r0 + tid];
    __syncthreads();

    const unsigned short* Be = Bt + (size_t)e * N * K;

    int lane = tid & 63;
    int wid = tid >> 6;
    int wm = (wid >> 1) * 32;
    int wn = (wid & 1) * 64;
    int colb_base = (lane >> 4) * 16;
    int lrow = lane & 15;

    f32x4_t acc[2][4] = {};

    auto stage = [&](int buf, int k0) {
        #pragma unroll
        for (int p = 0; p < 2; ++p) {
            int s = tid + p * 256;
            int r = s >> 3, c = s & 7;
            int gc = c ^ (r & 7);
            const void* asrc;
            if (GATHER) {
                int tok = toks[r];
                asrc = (tok >= 0) ? (const void*)(A + (size_t)tok * K + k0 + gc * 8)
                                  : (const void*)zrow;
            } else {
                asrc = (const void*)(A + (size_t)(r0 + r) * K + k0 + gc * 8);
            }
            gl_lds16(asrc, (char*)As[buf] + s * 16);
        }
        #pragma unroll
        for (int p = 0; p < 4; ++p) {
            int s = tid + p * 256;
            int r = s >> 3, c = s & 7;
            int gc = c ^ (r & 7);
            gl_lds16((const void*)(Be + (size_t)(n0 + r) * K + k0 + gc * 8),
                     (char*)Bs[buf] + s * 16);
        }
    };

    stage(0, 0);
    __syncthreads();       // drains prologue vmcnt

    int cur = 0;
    for (int k0 = 0; k0 < K; k0 += 64) {
        if (k0 + 64 < K) stage(cur ^ 1, k0 + 64);   // async prefetch into other buffer
        #pragma unroll
        for (int kk = 0; kk < 2; ++kk) {
            int colb = kk * 64 + colb_base;
            bf16x8_t a[2], b[4];
            #pragma unroll
            for (int i = 0; i < 2; ++i) {
                int ra = wm + i * 16 + lrow;
                a[i] = *(const bf16x8_t*)((const char*)As[cur] + ra * 128 + (colb ^ ((ra & 7) << 4)));
            }
            #pragma unroll
            for (int i = 0; i < 4; ++i) {
                int rb = wn + i * 16 + lrow;
                b[i] = *(const bf16x8_t*)((const char*)Bs[cur] + rb * 128 + (colb ^ ((rb & 7) << 4)));
            }
            #pragma unroll
            for (int mi = 0; mi < 2; ++mi)
                #pragma unroll
                for (int ni = 0; ni < 4; ++ni)
                    acc[mi][ni] = __builtin_amdgcn_mfma_f32_16x16x32_bf16(
                        a[mi], b[ni], acc[mi][ni], 0, 0, 0);
        }
        __syncthreads();   // vmcnt(0): prefetch landed; all waves done reading cur
        cur ^= 1;
    }

    #pragma unroll
    for (int mi = 0; mi < 2; ++mi) {
        #pragma unroll
        for (int ni = 0; ni < 4; ++ni) {
            int col = n0 + wn + ni * 16 + lrow;
            float bv = GELU ? bias[(size_t)e * N + col] : 0.f;
            #pragma unroll
            for (int j = 0; j < 4; ++j) {
                int row = r0 + wm + mi * 16 + (lane >> 4) * 4 + j;
                float v = acc[mi][ni][j] + bv;
                if (GELU) v = 0.5f * v * (1.f + erff(v * 0.70710678f));
                if (OUT_BF16)
                    ((unsigned short*)Cout)[(size_t)row * N + col] = f2bf(v);
                else
                    ((float*)Cout)[(size_t)row * N + col] = v;
            }
        }
    }
}

// ---------------- combine: out = x_res + sum_k g_k*(y[row_k] + b2[e_k]) ----------------
__global__ void combine_kernel(const float* __restrict__ x_res, const float* __restrict__ y,
                               const float* __restrict__ b2, const int* __restrict__ tok_e,
                               const float* __restrict__ tok_g, const int* __restrict__ tok_row,
                               float* __restrict__ out) {
    int t = blockIdx.x;
    int c = blockIdx.y * 256 + threadIdx.x;
    int e0 = tok_e[t*2], e1 = tok_e[t*2+1];
    float g0 = tok_g[t*2], g1 = tok_g[t*2+1];
    int r0 = tok_row[t*2], r1 = tok_row[t*2+1];
    float v = x_res[(size_t)t * DIMC + c]
            + g0 * (y[(size_t)r0 * DIMC + c] + b2[(size_t)e0 * DIMC + c])
            + g1 * (y[(size_t)r1 * DIMC + c] + b2[(size_t)e1 * DIMC + c]);
    out[(size_t)t * DIMC + c] = v;
}

extern "C" void kernel_launch(void* const* d_in, const int* in_sizes, int n_in,
                              void* d_out, int out_size, void* d_ws, size_t ws_size,
                              hipStream_t stream) {
    const float* x      = (const float*)d_in[0];
    const float* ln1_g  = (const float*)d_in[1];
    const float* ln1_b  = (const float*)d_in[2];
    const float* qkv_w  = (const float*)d_in[3];
    const float* qkv_b  = (const float*)d_in[4];
    const float* proj_w = (const float*)d_in[5];
    const float* proj_b = (const float*)d_in[6];
    const float* ln2_g  = (const float*)d_in[7];
    const float* ln2_b  = (const float*)d_in[8];
    const float* gate_w = (const float*)d_in[9];
    const float* w1     = (const float*)d_in[10];
    const float* b1     = (const float*)d_in[11];
    const float* w2     = (const float*)d_in[12];
    const float* b2     = (const float*)d_in[13];
    float* out = (float*)d_out;

    char* p = (char*)d_ws;
    auto alloc = [&](size_t nbytes) {
        void* r = (void*)p;
        p += (nbytes + 255) & ~(size_t)255;
        return r;
    };
    unsigned short* xn1_h   = (unsigned short*)alloc((size_t)TT * DIMC * 2);
    unsigned short* xn1_l   = (unsigned short*)alloc((size_t)TT * DIMC * 2);
    float*          qkv     = (float*)alloc((size_t)TT * 2304 * 4);
    unsigned short* ao_h    = (unsigned short*)alloc((size_t)TT * DIMC * 2);
    unsigned short* ao_l    = (unsigned short*)alloc((size_t)TT * DIMC * 2);
    float*          x_res   = (float*)alloc((size_t)TT * DIMC * 4);
    unsigned short* xn2_bf  = (unsigned short*)alloc((size_t)TT * DIMC * 2);
    unsigned short* h       = (unsigned short*)alloc((size_t)CAP_ROWS * HID * 2);
    float*          y       = (float*)alloc((size_t)CAP_ROWS * DIMC * 4);
    unsigned short* w1t     = (unsigned short*)alloc((size_t)EXPERTS * DIMC * HID * 2);
    unsigned short* w2t     = (unsigned short*)alloc((size_t)EXPERTS * DIMC * HID * 2);
    unsigned short* qwt_h   = (unsigned short*)alloc((size_t)DIMC * 2304 * 2);
    unsigned short* qwt_l   = (unsigned short*)alloc((size_t)DIMC * 2304 * 2);
    unsigned short* pwt_h   = (unsigned short*)alloc((size_t)DIMC * DIMC * 2);
    unsigned short* pwt_l   = (unsigned short*)alloc((size_t)DIMC * DIMC * 2);
    float*          tok_g   = (float*)alloc((size_t)2 * TT * 4);
    int*            tok_e   = (int*)alloc((size_t)2 * TT * 4);
    int*            tok_row = (int*)alloc((size_t)2 * TT * 4);
    int*            row2tok = (int*)alloc((size_t)CAP_ROWS * 4);
    unsigned short* zrow    = (unsigned short*)alloc(256);
    int*            counts  = (int*)alloc(32 * 4);
    int*            offsets = (int*)alloc(32 * 4);
    int*            cursor  = (int*)alloc(32 * 4);

    init_kernel<<<(CAP_ROWS + 255) / 256, 256, 0, stream>>>(counts, row2tok, CAP_ROWS, zrow);

    // weight transposes (independent of activations)
    transpose_bf16<<<dim3(HID / 64, DIMC / 64, EXPERTS), 256, 0, stream>>>(w1, w1t, DIMC, HID);
    transpose_bf16<<<dim3(DIMC / 64, HID / 64, EXPERTS), 256, 0, stream>>>(w2, w2t, HID, DIMC);
    transpose_split_bf16<<<dim3(2304 / 64, DIMC / 64), 256, 0, stream>>>(qkv_w, qwt_h, qwt_l,
                                                                         DIMC, 2304);
    transpose_split_bf16<<<dim3(DIMC / 64, DIMC / 64), 256, 0, stream>>>(proj_w, pwt_h, pwt_l,
                                                                         DIMC, DIMC);

    ln_kernel_t<0><<<TT, 256, 0, stream>>>(x, ln1_g, ln1_b, xn1_h, xn1_l,
                                           nullptr, nullptr, nullptr, nullptr);

    {
        int nmb = (TT + 63) / 64;                       // 25
        int nwg = nmb * (2304 / 64);                    // 900
        mfma_gemm_split<0><<<nwg, 256, 0, stream>>>(
            xn1_h, xn1_l, qwt_h, qwt_l, qkv_b, nullptr, qkv, zrow, TT, 2304, DIMC, nmb);
    }

    attn_mfma_kernel<<<dim3(BB * HEADS, 4), 512, 0, stream>>>(qkv, ao_h, ao_l);

    {
        int nmb = (TT + 63) / 64;                       // 25
        int nwg = nmb * (DIMC / 64);                    // 300
        mfma_gemm_split<1><<<nwg, 256, 0, stream>>>(
            ao_h, ao_l, pwt_h, pwt_l, proj_b, x, x_res, zrow, TT, DIMC, DIMC, nmb);
    }

    // ln2 with fused gate (logits in fp32, top-2 + softmax + counts)
    ln_kernel_t<1><<<TT, 256, 0, stream>>>(x_res, ln2_g, ln2_b, xn2_bf, nullptr,
                                           gate_w, tok_e, tok_g, counts);

    offsets_kernel<<<1, 64, 0, stream>>>(counts, offsets, cursor);

    fill_kernel<<<(TT + 255) / 256, 256, 0, stream>>>(tok_e, cursor, row2tok, tok_row);

    {
        int nxb = CAP_ROWS / 64;                        // 66
        int nwg1 = (HID / 128) * nxb;                   // 24*66 = 1584
        mfma_gemm_grouped<1, 1, 1><<<nwg1, 256, 0, stream>>>(
            xn2_bf, w1t, b1, offsets, row2tok, h, zrow, HID, DIMC, nxb);

        int nwg2 = (DIMC / 128) * nxb;                  // 6*66 = 396
        mfma_gemm_grouped<0, 0, 0><<<nwg2, 256, 0, stream>>>(
            h, w2t, nullptr, offsets, row2tok, y, zrow, DIMC, HID, nxb);
    }

    combine_kernel<<<dim3(TT, 3), 256, 0, stream>>>(x_res, y, b2, tok_e, tok_g, tok_row, out);
}

// Round 17
// 271.754 us; speedup vs baseline: 1.3890x; 1.0197x over previous
//
#include <hip/hip_runtime.h>
#include <hip/hip_bf16.h>
#include <math.h>

#define DIMC 768
#define HEADS 12
#define HD 64
#define EXPERTS 8
#define HID 3072
#define BB 8
#define NN 196
#define TT (BB*NN)      // 1568
#define CAP_ROWS 4224   // multiple of 64, >= 2*TT + 8*64 headroom
#define LN_EPS 1e-5f

typedef float f32x4_t __attribute__((ext_vector_type(4)));
typedef short bf16x8_t __attribute__((ext_vector_type(8)));
typedef unsigned short u16x8_t __attribute__((ext_vector_type(8)));

__device__ __forceinline__ unsigned short f2bf(float f) {
    unsigned int u = __float_as_uint(f);
    u += 0x7FFFu + ((u >> 16) & 1u);   // round-to-nearest-even
    return (unsigned short)(u >> 16);
}
__device__ __forceinline__ float bf2f(unsigned short u) {
    return __uint_as_float(((unsigned int)u) << 16);
}

// async global->LDS, 16B per lane; LDS dest = wave-uniform base + lane*16 (linear)
__device__ __forceinline__ void gl_lds16(const void* g, void* l) {
    __builtin_amdgcn_global_load_lds(
        (const __attribute__((address_space(1))) unsigned int*)g,
        (__attribute__((address_space(3))) unsigned int*)l, 16, 0, 0);
}

// bijective XCD-chunked remap (m204): physical bid -> logical L
__device__ __forceinline__ int xcd_remap(int pbid, int nwg) {
    int q = nwg >> 3, r8 = nwg & 7;
    int xcd = pbid & 7, slot = pbid >> 3;
    return (xcd < r8) ? xcd * (q + 1) + slot
                      : r8 * (q + 1) + (xcd - r8) * q + slot;
}

// ---------------- LayerNorm (+ optional fused gate): one block per token, 256 threads ----------------
template<int GATE>
__global__ void ln_kernel_t(const float* __restrict__ x, const float* __restrict__ g,
                            const float* __restrict__ b,
                            unsigned short* __restrict__ out_hi,
                            unsigned short* __restrict__ out_lo,
                            const float* __restrict__ gw, int* __restrict__ tok_e,
                            float* __restrict__ tok_g, int* __restrict__ counts) {
    int t = blockIdx.x;
    const float* xr = x + (size_t)t * DIMC;
    int tid = threadIdx.x;
    float v0 = xr[tid], v1 = xr[tid + 256], v2 = xr[tid + 512];
    __shared__ float red[256];
    red[tid] = v0 + v1 + v2;
    __syncthreads();
    for (int off = 128; off > 0; off >>= 1) {
        if (tid < off) red[tid] += red[tid + off];
        __syncthreads();
    }
    float mu = red[0] * (1.0f / DIMC);
    __syncthreads();
    float d0 = v0 - mu, d1 = v1 - mu, d2 = v2 - mu;
    red[tid] = d0*d0 + d1*d1 + d2*d2;
    __syncthreads();
    for (int off = 128; off > 0; off >>= 1) {
        if (tid < off) red[tid] += red[tid + off];
        __syncthreads();
    }
    float rstd = rsqrtf(red[0] * (1.0f / DIMC) + LN_EPS);
    float o0 = d0 * rstd * g[tid]       + b[tid];
    float o1 = d1 * rstd * g[tid + 256] + b[tid + 256];
    float o2 = d2 * rstd * g[tid + 512] + b[tid + 512];
    {
        unsigned short* o = out_hi + (size_t)t * DIMC;
        unsigned short h0 = f2bf(o0), h1 = f2bf(o1), h2 = f2bf(o2);
        o[tid] = h0; o[tid + 256] = h1; o[tid + 512] = h2;
        if (out_lo) {
            unsigned short* ol = out_lo + (size_t)t * DIMC;
            ol[tid]       = f2bf(o0 - bf2f(h0));
            ol[tid + 256] = f2bf(o1 - bf2f(h1));
            ol[tid + 512] = f2bf(o2 - bf2f(h2));
        }
    }
    if (GATE) {
        float p[8];
        const float* g0r = gw + (size_t)tid * 8;
        const float* g1r = gw + ((size_t)tid + 256) * 8;
        const float* g2r = gw + ((size_t)tid + 512) * 8;
        #pragma unroll
        for (int e = 0; e < 8; ++e)
            p[e] = o0 * g0r[e] + o1 * g1r[e] + o2 * g2r[e];
        #pragma unroll
        for (int off = 32; off > 0; off >>= 1)
            #pragma unroll
            for (int e = 0; e < 8; ++e) p[e] += __shfl_xor(p[e], off, 64);
        __shared__ float redw[4][8];
        int lane = tid & 63, w = tid >> 6;
        if (lane == 0) {
            #pragma unroll
            for (int e = 0; e < 8; ++e) redw[w][e] = p[e];
        }
        __syncthreads();
        if (tid == 0) {
            float lg[8];
            #pragma unroll
            for (int e = 0; e < 8; ++e)
                lg[e] = redw[0][e] + redw[1][e] + redw[2][e] + redw[3][e];
            int e0 = 0; float l0 = lg[0];
            #pragma unroll
            for (int e = 1; e < 8; ++e) if (lg[e] > l0) { l0 = lg[e]; e0 = e; }
            int e1 = -1; float l1 = -3e38f;
            #pragma unroll
            for (int e = 0; e < 8; ++e) if (e != e0 && lg[e] > l1) { l1 = lg[e]; e1 = e; }
            float pp = expf(l1 - l0);
            float ga = 1.f / (1.f + pp);
            float gb = pp / (1.f + pp);
            tok_e[t*2] = e0; tok_e[t*2+1] = e1;
            tok_g[t*2] = ga; tok_g[t*2+1] = gb;
            atomicAdd(&counts[e0], 1);
            atomicAdd(&counts[e1], 1);
        }
    }
}

// ---------------- MFMA attention, split-precision, 512 threads / 8 waves (validated r11) ----------------
__global__ void attn_mfma_kernel(const float* __restrict__ qkv,
                                 unsigned short* __restrict__ ao_h,
                                 unsigned short* __restrict__ ao_l) {
    __shared__ char psb[64 * 896];                         // 56 KB, swizzled fp32 [64][224]
    __shared__ unsigned short QsH[64 * 64], QsL[64 * 64];
    __shared__ unsigned short KsH[64 * 64], KsL[64 * 64];

    int bh = blockIdx.x;
    int b = bh / HEADS, h = bh % HEADS;
    int q0 = blockIdx.y * 64;
    const float* base = qkv + (size_t)b * NN * 2304 + h * 64;

    int tid = threadIdx.x;                 // 0..511
    int sr = tid >> 3, sq = tid & 7;
    int lane = tid & 63;
    int wid = tid >> 6;
    int wm = (wid >> 2) * 32;
    int wn = (wid & 3) * 16;
    int lrow = lane & 15;
    int lq = lane >> 4;
    int colb_base = lq * 16;

    {
        int r = sr;
        int n = q0 + r;
        float v[8] = {0.f,0.f,0.f,0.f,0.f,0.f,0.f,0.f};
        if (n < NN) {
            float4 a0 = *(const float4*)(base + (size_t)n * 2304 + sq * 8);
            float4 a1 = *(const float4*)(base + (size_t)n * 2304 + sq * 8 + 4);
            v[0]=a0.x; v[1]=a0.y; v[2]=a0.z; v[3]=a0.w;
            v[4]=a1.x; v[5]=a1.y; v[6]=a1.z; v[7]=a1.w;
        }
        u16x8_t hv, lv;
        #pragma unroll
        for (int t = 0; t < 8; ++t) {
            unsigned short hh = f2bf(v[t]);
            hv[t] = hh; lv[t] = f2bf(v[t] - bf2f(hh));
        }
        int off = r * 128 + ((sq * 16) ^ ((r & 7) << 4));
        *(u16x8_t*)((char*)QsH + off) = hv;
        *(u16x8_t*)((char*)QsL + off) = lv;
    }

    for (int kt = 0; kt < 4; ++kt) {
        int j0 = kt * 64;
        __syncthreads();
        {
            int r = sr;
            int n = j0 + r;
            float v[8] = {0.f,0.f,0.f,0.f,0.f,0.f,0.f,0.f};
            if (n < NN) {
                float4 a0 = *(const float4*)(base + (size_t)n * 2304 + 768 + sq * 8);
                float4 a1 = *(const float4*)(base + (size_t)n * 2304 + 768 + sq * 8 + 4);
                v[0]=a0.x; v[1]=a0.y; v[2]=a0.z; v[3]=a0.w;
                v[4]=a1.x; v[5]=a1.y; v[6]=a1.z; v[7]=a1.w;
            }
            u16x8_t hv, lv;
            #pragma unroll
            for (int t = 0; t < 8; ++t) {
                unsigned short hh = f2bf(v[t]);
                hv[t] = hh; lv[t] = f2bf(v[t] - bf2f(hh));
            }
            int off = r * 128 + ((sq * 16) ^ ((r & 7) << 4));
            *(u16x8_t*)((char*)KsH + off) = hv;
            *(u16x8_t*)((char*)KsL + off) = lv;
        }
        __syncthreads();

        f32x4_t acc[2] = {};
        #pragma unroll
        for (int kk = 0; kk < 2; ++kk) {
            int colb = kk * 64 + colb_base;
            bf16x8_t qh[2], ql[2], kh, kl;
            #pragma unroll
            for (int i = 0; i < 2; ++i) {
                int ra = wm + i * 16 + lrow;
                int oa = ra * 128 + (colb ^ ((ra & 7) << 4));
                qh[i] = *(const bf16x8_t*)((const char*)QsH + oa);
                ql[i] = *(const bf16x8_t*)((const char*)QsL + oa);
            }
            int rb = wn + lrow;
            int ob = rb * 128 + (colb ^ ((rb & 7) << 4));
            kh = *(const bf16x8_t*)((const char*)KsH + ob);
            kl = *(const bf16x8_t*)((const char*)KsL + ob);
            #pragma unroll
            for (int mi = 0; mi < 2; ++mi) {
                acc[mi] = __builtin_amdgcn_mfma_f32_16x16x32_bf16(qh[mi], kh, acc[mi], 0, 0, 0);
                acc[mi] = __builtin_amdgcn_mfma_f32_16x16x32_bf16(qh[mi], kl, acc[mi], 0, 0, 0);
                acc[mi] = __builtin_amdgcn_mfma_f32_16x16x32_bf16(ql[mi], kh, acc[mi], 0, 0, 0);
            }
        }
        int jc = j0 + wn + lrow;
        if (jc < 224) {
            #pragma unroll
            for (int mi = 0; mi < 2; ++mi) {
                #pragma unroll
                for (int j = 0; j < 4; ++j) {
                    int row = wm + mi * 16 + lq * 4 + j;
                    int s = (row & 7) ^ (row >> 3);
                    *(float*)(psb + row * 896 + ((jc * 4) ^ (s << 4))) = acc[mi][j] * 0.125f;
                }
            }
        }
    }
    __syncthreads();

    {
        int i = tid >> 3, l = tid & 7;
        int s = (i & 7) ^ (i >> 3);
        char* prow = psb + i * 896;
        float mx = -1e30f;
        for (int j = l; j < NN; j += 8) mx = fmaxf(mx, *(const float*)(prow + ((j * 4) ^ (s << 4))));
        mx = fmaxf(mx, __shfl_xor(mx, 1, 8));
        mx = fmaxf(mx, __shfl_xor(mx, 2, 8));
        mx = fmaxf(mx, __shfl_xor(mx, 4, 8));
        float sum = 0.f;
        for (int j = l; j < NN; j += 8) {
            float* pp = (float*)(prow + ((j * 4) ^ (s << 4)));
            float e = expf(*pp - mx); *pp = e; sum += e;
        }
        sum += __shfl_xor(sum, 1, 8);
        sum += __shfl_xor(sum, 2, 8);
        sum += __shfl_xor(sum, 4, 8);
        float inv = 1.f / sum;
        for (int j = l; j < NN; j += 8) {
            float* pp = (float*)(prow + ((j * 4) ^ (s << 4)));
            *pp *= inv;
        }
    }

    f32x4_t oacc[2] = {};
    for (int kt = 0; kt < 4; ++kt) {
        int j0 = kt * 64;
        __syncthreads();
        {
            int r = sr;
            int n = j0 + r;
            float v[8] = {0.f,0.f,0.f,0.f,0.f,0.f,0.f,0.f};
            if (n < NN) {
                float4 a0 = *(const float4*)(base + (size_t)n * 2304 + 1536 + sq * 8);
                float4 a1 = *(const float4*)(base + (size_t)n * 2304 + 1536 + sq * 8 + 4);
                v[0]=a0.x; v[1]=a0.y; v[2]=a0.z; v[3]=a0.w;
                v[4]=a1.x; v[5]=a1.y; v[6]=a1.z; v[7]=a1.w;
            }
            #pragma unroll
            for (int t = 0; t < 8; ++t) {
                int d = sq * 8 + t;
                int sw = ((d & 7) ^ (d >> 3)) << 4;
                unsigned short hh = f2bf(v[t]);
                int off = d * 128 + ((r * 2) ^ sw);
                *(unsigned short*)((char*)KsH + off) = hh;
                *(unsigned short*)((char*)KsL + off) = f2bf(v[t] - bf2f(hh));
            }
        }
        __syncthreads();

        int kkmax = (kt == 3) ? 1 : 2;
        for (int kk = 0; kk < kkmax; ++kk) {
            int colb = kk * 64 + colb_base;
            bf16x8_t pah[2], pal[2], vh, vl;
            #pragma unroll
            for (int i = 0; i < 2; ++i) {
                int ra = wm + i * 16 + lrow;
                int s = (ra & 7) ^ (ra >> 3);
                const char* prow = psb + ra * 896;
                int jb = (j0 + kk * 32 + lq * 8) * 4;
                float4 a0 = *(const float4*)(prow + (jb ^ (s << 4)));
                float4 a1 = *(const float4*)(prow + ((jb + 16) ^ (s << 4)));
                float vv[8] = {a0.x,a0.y,a0.z,a0.w,a1.x,a1.y,a1.z,a1.w};
                u16x8_t hv, lv;
                #pragma unroll
                for (int t = 0; t < 8; ++t) {
                    unsigned short hh = f2bf(vv[t]);
                    hv[t] = hh; lv[t] = f2bf(vv[t] - bf2f(hh));
                }
                pah[i] = *(bf16x8_t*)&hv;
                pal[i] = *(bf16x8_t*)&lv;
            }
            int rb = wn + lrow;
            int ob = rb * 128 + (colb ^ (((rb & 7) ^ (rb >> 3)) << 4));
            vh = *(const bf16x8_t*)((const char*)KsH + ob);
            vl = *(const bf16x8_t*)((const char*)KsL + ob);
            #pragma unroll
            for (int mi = 0; mi < 2; ++mi) {
                oacc[mi] = __builtin_amdgcn_mfma_f32_16x16x32_bf16(pah[mi], vh, oacc[mi], 0, 0, 0);
                oacc[mi] = __builtin_amdgcn_mfma_f32_16x16x32_bf16(pah[mi], vl, oacc[mi], 0, 0, 0);
                oacc[mi] = __builtin_amdgcn_mfma_f32_16x16x32_bf16(pal[mi], vh, oacc[mi], 0, 0, 0);
            }
        }
    }

    #pragma unroll
    for (int mi = 0; mi < 2; ++mi) {
        int col = h * 64 + wn + lrow;
        #pragma unroll
        for (int j = 0; j < 4; ++j) {
            int n = q0 + wm + mi * 16 + lq * 4 + j;
            if (n < NN) {
                float v = oacc[mi][j];
                unsigned short hh = f2bf(v);
                size_t o = (size_t)(b * NN + n) * DIMC + col;
                ao_h[o] = hh;
                ao_l[o] = f2bf(v - bf2f(hh));
            }
        }
    }
}

__global__ void init_kernel(int* __restrict__ counts, int* __restrict__ row2tok, int cap,
                            unsigned short* __restrict__ zrow) {
    int i = blockIdx.x * blockDim.x + threadIdx.x;
    if (i < 8) counts[i] = 0;
    if (i < 128) zrow[i] = 0;
    if (i < cap) row2tok[i] = -1;
}

__global__ void offsets_kernel(const int* __restrict__ counts, int* __restrict__ offsets,
                               int* __restrict__ cursor) {
    if (threadIdx.x == 0 && blockIdx.x == 0) {
        int off = 0;
        for (int e = 0; e < 8; ++e) {
            offsets[e] = off;
            cursor[e]  = off;
            off += ((counts[e] + 63) / 64) * 64;  // pad each segment to BM=64
        }
        offsets[8] = off;
    }
}

__global__ void fill_kernel(const int* __restrict__ tok_e, int* __restrict__ cursor,
                            int* __restrict__ row2tok, int* __restrict__ tok_row) {
    int t = blockIdx.x * blockDim.x + threadIdx.x;
    if (t >= TT) return;
    #pragma unroll
    for (int k = 0; k < 2; ++k) {
        int e = tok_e[t*2+k];
        int slot = atomicAdd(&cursor[e], 1);
        row2tok[slot] = t;
        tok_row[t*2+k] = slot;
    }
}

// ---------------- batched transpose + fp32->bf16: src [B][R][C] -> dst [B][C][R] ----------------
__global__ void transpose_bf16(const float* __restrict__ src, unsigned short* __restrict__ dst,
                               int R, int C) {
    __shared__ float tile[64][65];
    const float* s = src + (size_t)blockIdx.z * R * C;
    unsigned short* d = dst + (size_t)blockIdx.z * R * C;
    int c0 = blockIdx.x * 64, r0 = blockIdx.y * 64;
    int tid = threadIdx.x;
    int tr = tid >> 4;
    int tc = (tid & 15) * 4;
    #pragma unroll
    for (int p = 0; p < 4; ++p) {
        int r = tr + p * 16;
        const float4 v = *(const float4*)(s + (size_t)(r0 + r) * C + c0 + tc);
        tile[r][tc+0] = v.x; tile[r][tc+1] = v.y; tile[r][tc+2] = v.z; tile[r][tc+3] = v.w;
    }
    __syncthreads();
    #pragma unroll
    for (int p = 0; p < 4; ++p) {
        int c = tr + p * 16;
        ushort4 o;
        o.x = f2bf(tile[tc+0][c]);
        o.y = f2bf(tile[tc+1][c]);
        o.z = f2bf(tile[tc+2][c]);
        o.w = f2bf(tile[tc+3][c]);
        *(ushort4*)(d + (size_t)(c0 + c) * R + r0 + tc) = o;
    }
}

// ---------------- transpose + hi/lo split: src [R][C] fp32 -> dh/dl [C][R] bf16 ----------------
__global__ void transpose_split_bf16(const float* __restrict__ src,
                                     unsigned short* __restrict__ dh,
                                     unsigned short* __restrict__ dl, int R, int C) {
    __shared__ float tile[64][65];
    int c0 = blockIdx.x * 64, r0 = blockIdx.y * 64;
    int tid = threadIdx.x;
    int tr = tid >> 4;
    int tc = (tid & 15) * 4;
    #pragma unroll
    for (int p = 0; p < 4; ++p) {
        int r = tr + p * 16;
        const float4 v = *(const float4*)(src + (size_t)(r0 + r) * C + c0 + tc);
        tile[r][tc+0] = v.x; tile[r][tc+1] = v.y; tile[r][tc+2] = v.z; tile[r][tc+3] = v.w;
    }
    __syncthreads();
    #pragma unroll
    for (int p = 0; p < 4; ++p) {
        int c = tr + p * 16;
        ushort4 h, l;
        float v0 = tile[tc+0][c], v1 = tile[tc+1][c], v2 = tile[tc+2][c], v3 = tile[tc+3][c];
        h.x = f2bf(v0); l.x = f2bf(v0 - bf2f(h.x));
        h.y = f2bf(v1); l.y = f2bf(v1 - bf2f(h.y));
        h.z = f2bf(v2); l.z = f2bf(v2 - bf2f(h.z));
        h.w = f2bf(v3); l.w = f2bf(v3 - bf2f(h.w));
        size_t off = (size_t)(c0 + c) * R + r0 + tc;
        *(ushort4*)(dh + off) = h;
        *(ushort4*)(dl + off) = l;
    }
}

// ---------------- split-precision MFMA GEMM, gl_lds staging + XCD remap (validated r15/r16) ----------------
template<int RES>
__global__ void mfma_gemm_split(const unsigned short* __restrict__ Ah,
                                const unsigned short* __restrict__ Al,
                                const unsigned short* __restrict__ Bth,
                                const unsigned short* __restrict__ Btl,
                                const float* __restrict__ bias,
                                const float* __restrict__ res,
                                float* __restrict__ C,
                                const unsigned short* __restrict__ zrow,
                                int M, int N, int K, int nmb) {
    __shared__ unsigned short AsH[64 * 64];
    __shared__ unsigned short AsL[64 * 64];
    __shared__ unsigned short BsH[64 * 64];
    __shared__ unsigned short BsL[64 * 64];

    int L = xcd_remap(blockIdx.x, gridDim.x);
    int m0 = (L % nmb) * 64;
    int n0 = (L / nmb) * 64;
    int tid = threadIdx.x;
    int lane = tid & 63;
    int wid = tid >> 6;
    int wm = (wid >> 1) * 32;
    int wn = (wid & 1) * 32;
    int colb_base = (lane >> 4) * 16;
    int lrow = lane & 15;

    f32x4_t acc[2][2] = {};

    for (int k0 = 0; k0 < K; k0 += 64) {
        #pragma unroll
        for (int p = 0; p < 2; ++p) {
            int s = tid + p * 256;         // slot 0..511
            int r = s >> 3, c = s & 7;
            int gc = c ^ (r & 7);          // pre-swizzled source chunk
            bool inM = (m0 + r < M);
            size_t aoff = (size_t)(m0 + r) * K + k0 + gc * 8;
            gl_lds16(inM ? (const void*)(Ah + aoff) : (const void*)zrow, (char*)AsH + s * 16);
            gl_lds16(inM ? (const void*)(Al + aoff) : (const void*)zrow, (char*)AsL + s * 16);
            size_t boff = (size_t)(n0 + r) * K + k0 + gc * 8;
            gl_lds16((const void*)(Bth + boff), (char*)BsH + s * 16);
            gl_lds16((const void*)(Btl + boff), (char*)BsL + s * 16);
        }
        __syncthreads();
        #pragma unroll
        for (int kk = 0; kk < 2; ++kk) {
            int colb = kk * 64 + colb_base;
            bf16x8_t ah[2], al[2], bh[2], bl[2];
            #pragma unroll
            for (int i = 0; i < 2; ++i) {
                int ra = wm + i * 16 + lrow;
                int oa = ra * 128 + (colb ^ ((ra & 7) << 4));
                ah[i] = *(const bf16x8_t*)((const char*)AsH + oa);
                al[i] = *(const bf16x8_t*)((const char*)AsL + oa);
                int rb = wn + i * 16 + lrow;
                int ob = rb * 128 + (colb ^ ((rb & 7) << 4));
                bh[i] = *(const bf16x8_t*)((const char*)BsH + ob);
                bl[i] = *(const bf16x8_t*)((const char*)BsL + ob);
            }
            #pragma unroll
            for (int mi = 0; mi < 2; ++mi)
                #pragma unroll
                for (int ni = 0; ni < 2; ++ni) {
                    acc[mi][ni] = __builtin_amdgcn_mfma_f32_16x16x32_bf16(
                        ah[mi], bh[ni], acc[mi][ni], 0, 0, 0);
                    acc[mi][ni] = __builtin_amdgcn_mfma_f32_16x16x32_bf16(
                        ah[mi], bl[ni], acc[mi][ni], 0, 0, 0);
                    acc[mi][ni] = __builtin_amdgcn_mfma_f32_16x16x32_bf16(
                        al[mi], bh[ni], acc[mi][ni], 0, 0, 0);
                }
        }
        __syncthreads();
    }

    #pragma unroll
    for (int mi = 0; mi < 2; ++mi) {
        #pragma unroll
        for (int ni = 0; ni < 2; ++ni) {
            int col = n0 + wn + ni * 16 + lrow;
            #pragma unroll
            for (int j = 0; j < 4; ++j) {
                int row = m0 + wm + mi * 16 + (lane >> 4) * 4 + j;
                if (row < M) {
                    float v = acc[mi][ni][j] + bias[col];
                    if (RES) v += res[(size_t)row * N + col];
                    C[(size_t)row * N + col] = v;
                }
            }
        }
    }
}

// ---------------- grouped bf16 MFMA GEMM, 64x128 tile, BK=128, single buffer ----------------
// 4 waves 2x2 over (64 rows x 128 cols); each wave 32x64 = acc[2][4]. kk<4 over K=128 slice.
// Staging rows are 256B: slot s -> row s>>4, chunk s&15; source chunk gc = c ^ (r&7).
template<int GATHER, int GELU, int OUT_BF16>
__global__ void mfma_gemm_grouped(const unsigned short* __restrict__ A,
                                  const unsigned short* __restrict__ Bt,
                                  const float* __restrict__ bias,
                                  const int* __restrict__ offsets,
                                  const int* __restrict__ row2tok,
                                  void* __restrict__ Cout,
                                  const unsigned short* __restrict__ zrow,
                                  int N, int K, int nxb) {
    __shared__ unsigned short As[64 * 128];    // 16 KB, rows of 256B
    __shared__ unsigned short Bs[128 * 128];   // 32 KB, rows of 256B
    __shared__ int toks[64];

    int L = xcd_remap(blockIdx.x, gridDim.x);
    int xb = L % nxb;
    int n0 = (L / nxb) * 128;
    int r0 = xb * 64;
    if (r0 >= offsets[8]) return;
    int e = 0;
    while (r0 >= offsets[e + 1]) ++e;

    int tid = threadIdx.x;
    if (GATHER && tid < 64) toks[tid] = row2tok[r0 + tid];
    __syncthreads();

    const unsigned short* Be = Bt + (size_t)e * N * K;

    int lane = tid & 63;
    int wid = tid >> 6;
    int wm = (wid >> 1) * 32;
    int wn = (wid & 1) * 64;
    int colb_base = (lane >> 4) * 16;
    int lrow = lane & 15;

    f32x4_t acc[2][4] = {};

    for (int k0 = 0; k0 < K; k0 += 128) {
        // A: 64 rows x 128 el = 1024 slots of 16B (4/thread)
        #pragma unroll
        for (int p = 0; p < 4; ++p) {
            int s = tid + p * 256;
            int r = s >> 4, c = s & 15;
            int gc = c ^ (r & 7);
            const void* asrc;
            if (GATHER) {
                int tok = toks[r];
                asrc = (tok >= 0) ? (const void*)(A + (size_t)tok * K + k0 + gc * 8)
                                  : (const void*)zrow;
            } else {
                asrc = (const void*)(A + (size_t)(r0 + r) * K + k0 + gc * 8);
            }
            gl_lds16(asrc, (char*)As + s * 16);
        }
        // B: 128 rows x 128 el = 2048 slots (8/thread)
        #pragma unroll
        for (int p = 0; p < 8; ++p) {
            int s = tid + p * 256;
            int r = s >> 4, c = s & 15;
            int gc = c ^ (r & 7);
            gl_lds16((const void*)(Be + (size_t)(n0 + r) * K + k0 + gc * 8),
                     (char*)Bs + s * 16);
        }
        __syncthreads();
        #pragma unroll
        for (int kk = 0; kk < 4; ++kk) {
            int colb = kk * 64 + colb_base;
            bf16x8_t a[2], b[4];
            #pragma unroll
            for (int i = 0; i < 2; ++i) {
                int ra = wm + i * 16 + lrow;
                a[i] = *(const bf16x8_t*)((const char*)As + ra * 256 + (colb ^ ((ra & 7) << 4)));
            }
            #pragma unroll
            for (int i = 0; i < 4; ++i) {
                int rb = wn + i * 16 + lrow;
                b[i] = *(const bf16x8_t*)((const char*)Bs + rb * 256 + (colb ^ ((rb & 7) << 4)));
            }
            #pragma unroll
            for (int mi = 0; mi < 2; ++mi)
                #pragma unroll
                for (int ni = 0; ni < 4; ++ni)
                    acc[mi][ni] = __builtin_amdgcn_mfma_f32_16x16x32_bf16(
                        a[mi], b[ni], acc[mi][ni], 0, 0, 0);
        }
        __syncthreads();
    }

    #pragma unroll
    for (int mi = 0; mi < 2; ++mi) {
        #pragma unroll
        for (int ni = 0; ni < 4; ++ni) {
            int col = n0 + wn + ni * 16 + lrow;
            float bv = GELU ? bias[(size_t)e * N + col] : 0.f;
            #pragma unroll
            for (int j = 0; j < 4; ++j) {
                int row = r0 + wm + mi * 16 + (lane >> 4) * 4 + j;
                float v = acc[mi][ni][j] + bv;
                if (GELU) v = 0.5f * v * (1.f + erff(v * 0.70710678f));
                if (OUT_BF16)
                    ((unsigned short*)Cout)[(size_t)row * N + col] = f2bf(v);
                else
                    ((float*)Cout)[(size_t)row * N + col] = v;
            }
        }
    }
}

// ---------------- combine: out = x_res + sum_k g_k*(y[row_k] + b2[e_k]) ----------------
__global__ void combine_kernel(const float* __restrict__ x_res, const float* __restrict__ y,
                               const float* __restrict__ b2, const int* __restrict__ tok_e,
                               const float* __restrict__ tok_g, const int* __restrict__ tok_row,
                               float* __restrict__ out) {
    int t = blockIdx.x;
    int c = blockIdx.y * 256 + threadIdx.x;
    int e0 = tok_e[t*2], e1 = tok_e[t*2+1];
    float g0 = tok_g[t*2], g1 = tok_g[t*2+1];
    int r0 = tok_row[t*2], r1 = tok_row[t*2+1];
    float v = x_res[(size_t)t * DIMC + c]
            + g0 * (y[(size_t)r0 * DIMC + c] + b2[(size_t)e0 * DIMC + c])
            + g1 * (y[(size_t)r1 * DIMC + c] + b2[(size_t)e1 * DIMC + c]);
    out[(size_t)t * DIMC + c] = v;
}

extern "C" void kernel_launch(void* const* d_in, const int* in_sizes, int n_in,
                              void* d_out, int out_size, void* d_ws, size_t ws_size,
                              hipStream_t stream) {
    const float* x      = (const float*)d_in[0];
    const float* ln1_g  = (const float*)d_in[1];
    const float* ln1_b  = (const float*)d_in[2];
    const float* qkv_w  = (const float*)d_in[3];
    const float* qkv_b  = (const float*)d_in[4];
    const float* proj_w = (const float*)d_in[5];
    const float* proj_b = (const float*)d_in[6];
    const float* ln2_g  = (const float*)d_in[7];
    const float* ln2_b  = (const float*)d_in[8];
    const float* gate_w = (const float*)d_in[9];
    const float* w1     = (const float*)d_in[10];
    const float* b1     = (const float*)d_in[11];
    const float* w2     = (const float*)d_in[12];
    const float* b2     = (const float*)d_in[13];
    float* out = (float*)d_out;

    char* p = (char*)d_ws;
    auto alloc = [&](size_t nbytes) {
        void* r = (void*)p;
        p += (nbytes + 255) & ~(size_t)255;
        return r;
    };
    unsigned short* xn1_h   = (unsigned short*)alloc((size_t)TT * DIMC * 2);
    unsigned short* xn1_l   = (unsigned short*)alloc((size_t)TT * DIMC * 2);
    float*          qkv     = (float*)alloc((size_t)TT * 2304 * 4);
    unsigned short* ao_h    = (unsigned short*)alloc((size_t)TT * DIMC * 2);
    unsigned short* ao_l    = (unsigned short*)alloc((size_t)TT * DIMC * 2);
    float*          x_res   = (float*)alloc((size_t)TT * DIMC * 4);
    unsigned short* xn2_bf  = (unsigned short*)alloc((size_t)TT * DIMC * 2);
    unsigned short* h       = (unsigned short*)alloc((size_t)CAP_ROWS * HID * 2);
    float*          y       = (float*)alloc((size_t)CAP_ROWS * DIMC * 4);
    unsigned short* w1t     = (unsigned short*)alloc((size_t)EXPERTS * DIMC * HID * 2);
    unsigned short* w2t     = (unsigned short*)alloc((size_t)EXPERTS * DIMC * HID * 2);
    unsigned short* qwt_h   = (unsigned short*)alloc((size_t)DIMC * 2304 * 2);
    unsigned short* qwt_l   = (unsigned short*)alloc((size_t)DIMC * 2304 * 2);
    unsigned short* pwt_h   = (unsigned short*)alloc((size_t)DIMC * DIMC * 2);
    unsigned short* pwt_l   = (unsigned short*)alloc((size_t)DIMC * DIMC * 2);
    float*          tok_g   = (float*)alloc((size_t)2 * TT * 4);
    int*            tok_e   = (int*)alloc((size_t)2 * TT * 4);
    int*            tok_row = (int*)alloc((size_t)2 * TT * 4);
    int*            row2tok = (int*)alloc((size_t)CAP_ROWS * 4);
    unsigned short* zrow    = (unsigned short*)alloc(256);
    int*            counts  = (int*)alloc(32 * 4);
    int*            offsets = (int*)alloc(32 * 4);
    int*            cursor  = (int*)alloc(32 * 4);

    init_kernel<<<(CAP_ROWS + 255) / 256, 256, 0, stream>>>(counts, row2tok, CAP_ROWS, zrow);

    // weight transposes (independent of activations)
    transpose_bf16<<<dim3(HID / 64, DIMC / 64, EXPERTS), 256, 0, stream>>>(w1, w1t, DIMC, HID);
    transpose_bf16<<<dim3(DIMC / 64, HID / 64, EXPERTS), 256, 0, stream>>>(w2, w2t, HID, DIMC);
    transpose_split_bf16<<<dim3(2304 / 64, DIMC / 64), 256, 0, stream>>>(qkv_w, qwt_h, qwt_l,
                                                                         DIMC, 2304);
    transpose_split_bf16<<<dim3(DIMC / 64, DIMC / 64), 256, 0, stream>>>(proj_w, pwt_h, pwt_l,
                                                                         DIMC, DIMC);

    ln_kernel_t<0><<<TT, 256, 0, stream>>>(x, ln1_g, ln1_b, xn1_h, xn1_l,
                                           nullptr, nullptr, nullptr, nullptr);

    {
        int nmb = (TT + 63) / 64;                       // 25
        int nwg = nmb * (2304 / 64);                    // 900
        mfma_gemm_split<0><<<nwg, 256, 0, stream>>>(
            xn1_h, xn1_l, qwt_h, qwt_l, qkv_b, nullptr, qkv, zrow, TT, 2304, DIMC, nmb);
    }

    attn_mfma_kernel<<<dim3(BB * HEADS, 4), 512, 0, stream>>>(qkv, ao_h, ao_l);

    {
        int nmb = (TT + 63) / 64;                       // 25
        int nwg = nmb * (DIMC / 64);                    // 300
        mfma_gemm_split<1><<<nwg, 256, 0, stream>>>(
            ao_h, ao_l, pwt_h, pwt_l, proj_b, x, x_res, zrow, TT, DIMC, DIMC, nmb);
    }

    // ln2 with fused gate (logits in fp32, top-2 + softmax + counts)
    ln_kernel_t<1><<<TT, 256, 0, stream>>>(x_res, ln2_g, ln2_b, xn2_bf, nullptr,
                                           gate_w, tok_e, tok_g, counts);

    offsets_kernel<<<1, 64, 0, stream>>>(counts, offsets, cursor);

    fill_kernel<<<(TT + 255) / 256, 256, 0, stream>>>(tok_e, cursor, row2tok, tok_row);

    {
        int nxb = CAP_ROWS / 64;                        // 66
        int nwg1 = (HID / 128) * nxb;                   // 24*66 = 1584
        mfma_gemm_grouped<1, 1, 1><<<nwg1, 256, 0, stream>>>(
            xn2_bf, w1t, b1, offsets, row2tok, h, zrow, HID, DIMC, nxb);

        int nwg2 = (DIMC / 128) * nxb;                  // 6*66 = 396
        mfma_gemm_grouped<0, 0, 0><<<nwg2, 256, 0, stream>>>(
            h, w2t, nullptr, offsets, row2tok, y, zrow, DIMC, HID, nxb);
    }

    combine_kernel<<<dim3(TT, 3), 256, 0, stream>>>(x_res, y, b2, tok_e, tok_g, tok_row, out);
}

// Round 18
// 266.455 us; speedup vs baseline: 1.4166x; 1.0199x over previous
//
#include <hip/hip_runtime.h>
#include <hip/hip_bf16.h>
#include <math.h>

#define DIMC 768
#define HEADS 12
#define HD 64
#define EXPERTS 8
#define HID 3072
#define BB 8
#define NN 196
#define TT (BB*NN)      // 1568
#define CAP_ROWS 4224   // multiple of 128, >= 2*TT + 8*128 headroom
#define LN_EPS 1e-5f

typedef float f32x4_t __attribute__((ext_vector_type(4)));
typedef short bf16x8_t __attribute__((ext_vector_type(8)));
typedef unsigned short u16x8_t __attribute__((ext_vector_type(8)));

__device__ __forceinline__ unsigned short f2bf(float f) {
    unsigned int u = __float_as_uint(f);
    u += 0x7FFFu + ((u >> 16) & 1u);   // round-to-nearest-even
    return (unsigned short)(u >> 16);
}
__device__ __forceinline__ float bf2f(unsigned short u) {
    return __uint_as_float(((unsigned int)u) << 16);
}

// async global->LDS, 16B per lane; LDS dest = wave-uniform base + lane*16 (linear)
__device__ __forceinline__ void gl_lds16(const void* g, void* l) {
    __builtin_amdgcn_global_load_lds(
        (const __attribute__((address_space(1))) unsigned int*)g,
        (__attribute__((address_space(3))) unsigned int*)l, 16, 0, 0);
}

// bijective XCD-chunked remap (m204): physical bid -> logical L
__device__ __forceinline__ int xcd_remap(int pbid, int nwg) {
    int q = nwg >> 3, r8 = nwg & 7;
    int xcd = pbid & 7, slot = pbid >> 3;
    return (xcd < r8) ? xcd * (q + 1) + slot
                      : r8 * (q + 1) + (xcd - r8) * q + slot;
}

// ---------------- LayerNorm (+ optional fused gate): one block per token, 256 threads ----------------
template<int GATE>
__global__ void ln_kernel_t(const float* __restrict__ x, const float* __restrict__ g,
                            const float* __restrict__ b,
                            unsigned short* __restrict__ out_hi,
                            unsigned short* __restrict__ out_lo,
                            const float* __restrict__ gw, int* __restrict__ tok_e,
                            float* __restrict__ tok_g, int* __restrict__ counts) {
    int t = blockIdx.x;
    const float* xr = x + (size_t)t * DIMC;
    int tid = threadIdx.x;
    float v0 = xr[tid], v1 = xr[tid + 256], v2 = xr[tid + 512];
    __shared__ float red[256];
    red[tid] = v0 + v1 + v2;
    __syncthreads();
    for (int off = 128; off > 0; off >>= 1) {
        if (tid < off) red[tid] += red[tid + off];
        __syncthreads();
    }
    float mu = red[0] * (1.0f / DIMC);
    __syncthreads();
    float d0 = v0 - mu, d1 = v1 - mu, d2 = v2 - mu;
    red[tid] = d0*d0 + d1*d1 + d2*d2;
    __syncthreads();
    for (int off = 128; off > 0; off >>= 1) {
        if (tid < off) red[tid] += red[tid + off];
        __syncthreads();
    }
    float rstd = rsqrtf(red[0] * (1.0f / DIMC) + LN_EPS);
    float o0 = d0 * rstd * g[tid]       + b[tid];
    float o1 = d1 * rstd * g[tid + 256] + b[tid + 256];
    float o2 = d2 * rstd * g[tid + 512] + b[tid + 512];
    {
        unsigned short* o = out_hi + (size_t)t * DIMC;
        unsigned short h0 = f2bf(o0), h1 = f2bf(o1), h2 = f2bf(o2);
        o[tid] = h0; o[tid + 256] = h1; o[tid + 512] = h2;
        if (out_lo) {
            unsigned short* ol = out_lo + (size_t)t * DIMC;
            ol[tid]       = f2bf(o0 - bf2f(h0));
            ol[tid + 256] = f2bf(o1 - bf2f(h1));
            ol[tid + 512] = f2bf(o2 - bf2f(h2));
        }
    }
    if (GATE) {
        float p[8];
        const float* g0r = gw + (size_t)tid * 8;
        const float* g1r = gw + ((size_t)tid + 256) * 8;
        const float* g2r = gw + ((size_t)tid + 512) * 8;
        #pragma unroll
        for (int e = 0; e < 8; ++e)
            p[e] = o0 * g0r[e] + o1 * g1r[e] + o2 * g2r[e];
        #pragma unroll
        for (int off = 32; off > 0; off >>= 1)
            #pragma unroll
            for (int e = 0; e < 8; ++e) p[e] += __shfl_xor(p[e], off, 64);
        __shared__ float redw[4][8];
        int lane = tid & 63, w = tid >> 6;
        if (lane == 0) {
            #pragma unroll
            for (int e = 0; e < 8; ++e) redw[w][e] = p[e];
        }
        __syncthreads();
        if (tid == 0) {
            float lg[8];
            #pragma unroll
            for (int e = 0; e < 8; ++e)
                lg[e] = redw[0][e] + redw[1][e] + redw[2][e] + redw[3][e];
            int e0 = 0; float l0 = lg[0];
            #pragma unroll
            for (int e = 1; e < 8; ++e) if (lg[e] > l0) { l0 = lg[e]; e0 = e; }
            int e1 = -1; float l1 = -3e38f;
            #pragma unroll
            for (int e = 0; e < 8; ++e) if (e != e0 && lg[e] > l1) { l1 = lg[e]; e1 = e; }
            float pp = expf(l1 - l0);
            float ga = 1.f / (1.f + pp);
            float gb = pp / (1.f + pp);
            tok_e[t*2] = e0; tok_e[t*2+1] = e1;
            tok_g[t*2] = ga; tok_g[t*2+1] = gb;
            atomicAdd(&counts[e0], 1);
            atomicAdd(&counts[e1], 1);
        }
    }
}

// ---------------- MFMA attention, split-precision, 512 threads / 8 waves (validated r11) ----------------
__global__ void attn_mfma_kernel(const float* __restrict__ qkv,
                                 unsigned short* __restrict__ ao_h,
                                 unsigned short* __restrict__ ao_l) {
    __shared__ char psb[64 * 896];                         // 56 KB, swizzled fp32 [64][224]
    __shared__ unsigned short QsH[64 * 64], QsL[64 * 64];
    __shared__ unsigned short KsH[64 * 64], KsL[64 * 64];

    int bh = blockIdx.x;
    int b = bh / HEADS, h = bh % HEADS;
    int q0 = blockIdx.y * 64;
    const float* base = qkv + (size_t)b * NN * 2304 + h * 64;

    int tid = threadIdx.x;                 // 0..511
    int sr = tid >> 3, sq = tid & 7;
    int lane = tid & 63;
    int wid = tid >> 6;
    int wm = (wid >> 2) * 32;
    int wn = (wid & 3) * 16;
    int lrow = lane & 15;
    int lq = lane >> 4;
    int colb_base = lq * 16;

    {
        int r = sr;
        int n = q0 + r;
        float v[8] = {0.f,0.f,0.f,0.f,0.f,0.f,0.f,0.f};
        if (n < NN) {
            float4 a0 = *(const float4*)(base + (size_t)n * 2304 + sq * 8);
            float4 a1 = *(const float4*)(base + (size_t)n * 2304 + sq * 8 + 4);
            v[0]=a0.x; v[1]=a0.y; v[2]=a0.z; v[3]=a0.w;
            v[4]=a1.x; v[5]=a1.y; v[6]=a1.z; v[7]=a1.w;
        }
        u16x8_t hv, lv;
        #pragma unroll
        for (int t = 0; t < 8; ++t) {
            unsigned short hh = f2bf(v[t]);
            hv[t] = hh; lv[t] = f2bf(v[t] - bf2f(hh));
        }
        int off = r * 128 + ((sq * 16) ^ ((r & 7) << 4));
        *(u16x8_t*)((char*)QsH + off) = hv;
        *(u16x8_t*)((char*)QsL + off) = lv;
    }

    for (int kt = 0; kt < 4; ++kt) {
        int j0 = kt * 64;
        __syncthreads();
        {
            int r = sr;
            int n = j0 + r;
            float v[8] = {0.f,0.f,0.f,0.f,0.f,0.f,0.f,0.f};
            if (n < NN) {
                float4 a0 = *(const float4*)(base + (size_t)n * 2304 + 768 + sq * 8);
                float4 a1 = *(const float4*)(base + (size_t)n * 2304 + 768 + sq * 8 + 4);
                v[0]=a0.x; v[1]=a0.y; v[2]=a0.z; v[3]=a0.w;
                v[4]=a1.x; v[5]=a1.y; v[6]=a1.z; v[7]=a1.w;
            }
            u16x8_t hv, lv;
            #pragma unroll
            for (int t = 0; t < 8; ++t) {
                unsigned short hh = f2bf(v[t]);
                hv[t] = hh; lv[t] = f2bf(v[t] - bf2f(hh));
            }
            int off = r * 128 + ((sq * 16) ^ ((r & 7) << 4));
            *(u16x8_t*)((char*)KsH + off) = hv;
            *(u16x8_t*)((char*)KsL + off) = lv;
        }
        __syncthreads();

        f32x4_t acc[2] = {};
        #pragma unroll
        for (int kk = 0; kk < 2; ++kk) {
            int colb = kk * 64 + colb_base;
            bf16x8_t qh[2], ql[2], kh, kl;
            #pragma unroll
            for (int i = 0; i < 2; ++i) {
                int ra = wm + i * 16 + lrow;
                int oa = ra * 128 + (colb ^ ((ra & 7) << 4));
                qh[i] = *(const bf16x8_t*)((const char*)QsH + oa);
                ql[i] = *(const bf16x8_t*)((const char*)QsL + oa);
            }
            int rb = wn + lrow;
            int ob = rb * 128 + (colb ^ ((rb & 7) << 4));
            kh = *(const bf16x8_t*)((const char*)KsH + ob);
            kl = *(const bf16x8_t*)((const char*)KsL + ob);
            #pragma unroll
            for (int mi = 0; mi < 2; ++mi) {
                acc[mi] = __builtin_amdgcn_mfma_f32_16x16x32_bf16(qh[mi], kh, acc[mi], 0, 0, 0);
                acc[mi] = __builtin_amdgcn_mfma_f32_16x16x32_bf16(qh[mi], kl, acc[mi], 0, 0, 0);
                acc[mi] = __builtin_amdgcn_mfma_f32_16x16x32_bf16(ql[mi], kh, acc[mi], 0, 0, 0);
            }
        }
        int jc = j0 + wn + lrow;
        if (jc < 224) {
            #pragma unroll
            for (int mi = 0; mi < 2; ++mi) {
                #pragma unroll
                for (int j = 0; j < 4; ++j) {
                    int row = wm + mi * 16 + lq * 4 + j;
                    int s = (row & 7) ^ (row >> 3);
                    *(float*)(psb + row * 896 + ((jc * 4) ^ (s << 4))) = acc[mi][j] * 0.125f;
                }
            }
        }
    }
    __syncthreads();

    {
        int i = tid >> 3, l = tid & 7;
        int s = (i & 7) ^ (i >> 3);
        char* prow = psb + i * 896;
        float mx = -1e30f;
        for (int j = l; j < NN; j += 8) mx = fmaxf(mx, *(const float*)(prow + ((j * 4) ^ (s << 4))));
        mx = fmaxf(mx, __shfl_xor(mx, 1, 8));
        mx = fmaxf(mx, __shfl_xor(mx, 2, 8));
        mx = fmaxf(mx, __shfl_xor(mx, 4, 8));
        float sum = 0.f;
        for (int j = l; j < NN; j += 8) {
            float* pp = (float*)(prow + ((j * 4) ^ (s << 4)));
            float e = expf(*pp - mx); *pp = e; sum += e;
        }
        sum += __shfl_xor(sum, 1, 8);
        sum += __shfl_xor(sum, 2, 8);
        sum += __shfl_xor(sum, 4, 8);
        float inv = 1.f / sum;
        for (int j = l; j < NN; j += 8) {
            float* pp = (float*)(prow + ((j * 4) ^ (s << 4)));
            *pp *= inv;
        }
    }

    f32x4_t oacc[2] = {};
    for (int kt = 0; kt < 4; ++kt) {
        int j0 = kt * 64;
        __syncthreads();
        {
            int r = sr;
            int n = j0 + r;
            float v[8] = {0.f,0.f,0.f,0.f,0.f,0.f,0.f,0.f};
            if (n < NN) {
                float4 a0 = *(const float4*)(base + (size_t)n * 2304 + 1536 + sq * 8);
                float4 a1 = *(const float4*)(base + (size_t)n * 2304 + 1536 + sq * 8 + 4);
                v[0]=a0.x; v[1]=a0.y; v[2]=a0.z; v[3]=a0.w;
                v[4]=a1.x; v[5]=a1.y; v[6]=a1.z; v[7]=a1.w;
            }
            #pragma unroll
            for (int t = 0; t < 8; ++t) {
                int d = sq * 8 + t;
                int sw = ((d & 7) ^ (d >> 3)) << 4;
                unsigned short hh = f2bf(v[t]);
                int off = d * 128 + ((r * 2) ^ sw);
                *(unsigned short*)((char*)KsH + off) = hh;
                *(unsigned short*)((char*)KsL + off) = f2bf(v[t] - bf2f(hh));
            }
        }
        __syncthreads();

        int kkmax = (kt == 3) ? 1 : 2;
        for (int kk = 0; kk < kkmax; ++kk) {
            int colb = kk * 64 + colb_base;
            bf16x8_t pah[2], pal[2], vh, vl;
            #pragma unroll
            for (int i = 0; i < 2; ++i) {
                int ra = wm + i * 16 + lrow;
                int s = (ra & 7) ^ (ra >> 3);
                const char* prow = psb + ra * 896;
                int jb = (j0 + kk * 32 + lq * 8) * 4;
                float4 a0 = *(const float4*)(prow + (jb ^ (s << 4)));
                float4 a1 = *(const float4*)(prow + ((jb + 16) ^ (s << 4)));
                float vv[8] = {a0.x,a0.y,a0.z,a0.w,a1.x,a1.y,a1.z,a1.w};
                u16x8_t hv, lv;
                #pragma unroll
                for (int t = 0; t < 8; ++t) {
                    unsigned short hh = f2bf(vv[t]);
                    hv[t] = hh; lv[t] = f2bf(vv[t] - bf2f(hh));
                }
                pah[i] = *(bf16x8_t*)&hv;
                pal[i] = *(bf16x8_t*)&lv;
            }
            int rb = wn + lrow;
            int ob = rb * 128 + (colb ^ (((rb & 7) ^ (rb >> 3)) << 4));
            vh = *(const bf16x8_t*)((const char*)KsH + ob);
            vl = *(const bf16x8_t*)((const char*)KsL + ob);
            #pragma unroll
            for (int mi = 0; mi < 2; ++mi) {
                oacc[mi] = __builtin_amdgcn_mfma_f32_16x16x32_bf16(pah[mi], vh, oacc[mi], 0, 0, 0);
                oacc[mi] = __builtin_amdgcn_mfma_f32_16x16x32_bf16(pah[mi], vl, oacc[mi], 0, 0, 0);
                oacc[mi] = __builtin_amdgcn_mfma_f32_16x16x32_bf16(pal[mi], vh, oacc[mi], 0, 0, 0);
            }
        }
    }

    #pragma unroll
    for (int mi = 0; mi < 2; ++mi) {
        int col = h * 64 + wn + lrow;
        #pragma unroll
        for (int j = 0; j < 4; ++j) {
            int n = q0 + wm + mi * 16 + lq * 4 + j;
            if (n < NN) {
                float v = oacc[mi][j];
                unsigned short hh = f2bf(v);
                size_t o = (size_t)(b * NN + n) * DIMC + col;
                ao_h[o] = hh;
                ao_l[o] = f2bf(v - bf2f(hh));
            }
        }
    }
}

__global__ void init_kernel(int* __restrict__ counts, int* __restrict__ row2tok, int cap,
                            unsigned short* __restrict__ zrow) {
    int i = blockIdx.x * blockDim.x + threadIdx.x;
    if (i < 8) counts[i] = 0;
    if (i < 128) zrow[i] = 0;
    if (i < cap) row2tok[i] = -1;
}

__global__ void offsets_kernel(const int* __restrict__ counts, int* __restrict__ offsets,
                               int* __restrict__ cursor) {
    if (threadIdx.x == 0 && blockIdx.x == 0) {
        int off = 0;
        for (int e = 0; e < 8; ++e) {
            offsets[e] = off;
            cursor[e]  = off;
            off += ((counts[e] + 127) / 128) * 128;  // pad each segment to BM=128 (e1 tile)
        }
        offsets[8] = off;
    }
}

__global__ void fill_kernel(const int* __restrict__ tok_e, int* __restrict__ cursor,
                            int* __restrict__ row2tok, int* __restrict__ tok_row) {
    int t = blockIdx.x * blockDim.x + threadIdx.x;
    if (t >= TT) return;
    #pragma unroll
    for (int k = 0; k < 2; ++k) {
        int e = tok_e[t*2+k];
        int slot = atomicAdd(&cursor[e], 1);
        row2tok[slot] = t;
        tok_row[t*2+k] = slot;
    }
}

// ---------------- batched transpose + fp32->bf16: src [B][R][C] -> dst [B][C][R] ----------------
__global__ void transpose_bf16(const float* __restrict__ src, unsigned short* __restrict__ dst,
                               int R, int C) {
    __shared__ float tile[64][65];
    const float* s = src + (size_t)blockIdx.z * R * C;
    unsigned short* d = dst + (size_t)blockIdx.z * R * C;
    int c0 = blockIdx.x * 64, r0 = blockIdx.y * 64;
    int tid = threadIdx.x;
    int tr = tid >> 4;
    int tc = (tid & 15) * 4;
    #pragma unroll
    for (int p = 0; p < 4; ++p) {
        int r = tr + p * 16;
        const float4 v = *(const float4*)(s + (size_t)(r0 + r) * C + c0 + tc);
        tile[r][tc+0] = v.x; tile[r][tc+1] = v.y; tile[r][tc+2] = v.z; tile[r][tc+3] = v.w;
    }
    __syncthreads();
    #pragma unroll
    for (int p = 0; p < 4; ++p) {
        int c = tr + p * 16;
        ushort4 o;
        o.x = f2bf(tile[tc+0][c]);
        o.y = f2bf(tile[tc+1][c]);
        o.z = f2bf(tile[tc+2][c]);
        o.w = f2bf(tile[tc+3][c]);
        *(ushort4*)(d + (size_t)(c0 + c) * R + r0 + tc) = o;
    }
}

// ---------------- transpose + hi/lo split: src [R][C] fp32 -> dh/dl [C][R] bf16 ----------------
__global__ void transpose_split_bf16(const float* __restrict__ src,
                                     unsigned short* __restrict__ dh,
                                     unsigned short* __restrict__ dl, int R, int C) {
    __shared__ float tile[64][65];
    int c0 = blockIdx.x * 64, r0 = blockIdx.y * 64;
    int tid = threadIdx.x;
    int tr = tid >> 4;
    int tc = (tid & 15) * 4;
    #pragma unroll
    for (int p = 0; p < 4; ++p) {
        int r = tr + p * 16;
        const float4 v = *(const float4*)(src + (size_t)(r0 + r) * C + c0 + tc);
        tile[r][tc+0] = v.x; tile[r][tc+1] = v.y; tile[r][tc+2] = v.z; tile[r][tc+3] = v.w;
    }
    __syncthreads();
    #pragma unroll
    for (int p = 0; p < 4; ++p) {
        int c = tr + p * 16;
        ushort4 h, l;
        float v0 = tile[tc+0][c], v1 = tile[tc+1][c], v2 = tile[tc+2][c], v3 = tile[tc+3][c];
        h.x = f2bf(v0); l.x = f2bf(v0 - bf2f(h.x));
        h.y = f2bf(v1); l.y = f2bf(v1 - bf2f(h.y));
        h.z = f2bf(v2); l.z = f2bf(v2 - bf2f(h.z));
        h.w = f2bf(v3); l.w = f2bf(v3 - bf2f(h.w));
        size_t off = (size_t)(c0 + c) * R + r0 + tc;
        *(ushort4*)(dh + off) = h;
        *(ushort4*)(dl + off) = l;
    }
}

// ---------------- split-precision MFMA GEMM, gl_lds staging + XCD remap (validated r15-r17) ----------------
template<int RES>
__global__ void mfma_gemm_split(const unsigned short* __restrict__ Ah,
                                const unsigned short* __restrict__ Al,
                                const unsigned short* __restrict__ Bth,
                                const unsigned short* __restrict__ Btl,
                                const float* __restrict__ bias,
                                const float* __restrict__ res,
                                float* __restrict__ C,
                                const unsigned short* __restrict__ zrow,
                                int M, int N, int K, int nmb) {
    __shared__ unsigned short AsH[64 * 64];
    __shared__ unsigned short AsL[64 * 64];
    __shared__ unsigned short BsH[64 * 64];
    __shared__ unsigned short BsL[64 * 64];

    int L = xcd_remap(blockIdx.x, gridDim.x);
    int m0 = (L % nmb) * 64;
    int n0 = (L / nmb) * 64;
    int tid = threadIdx.x;
    int lane = tid & 63;
    int wid = tid >> 6;
    int wm = (wid >> 1) * 32;
    int wn = (wid & 1) * 32;
    int colb_base = (lane >> 4) * 16;
    int lrow = lane & 15;

    f32x4_t acc[2][2] = {};

    for (int k0 = 0; k0 < K; k0 += 64) {
        #pragma unroll
        for (int p = 0; p < 2; ++p) {
            int s = tid + p * 256;         // slot 0..511
            int r = s >> 3, c = s & 7;
            int gc = c ^ (r & 7);          // pre-swizzled source chunk
            bool inM = (m0 + r < M);
            size_t aoff = (size_t)(m0 + r) * K + k0 + gc * 8;
            gl_lds16(inM ? (const void*)(Ah + aoff) : (const void*)zrow, (char*)AsH + s * 16);
            gl_lds16(inM ? (const void*)(Al + aoff) : (const void*)zrow, (char*)AsL + s * 16);
            size_t boff = (size_t)(n0 + r) * K + k0 + gc * 8;
            gl_lds16((const void*)(Bth + boff), (char*)BsH + s * 16);
            gl_lds16((const void*)(Btl + boff), (char*)BsL + s * 16);
        }
        __syncthreads();
        #pragma unroll
        for (int kk = 0; kk < 2; ++kk) {
            int colb = kk * 64 + colb_base;
            bf16x8_t ah[2], al[2], bh[2], bl[2];
            #pragma unroll
            for (int i = 0; i < 2; ++i) {
                int ra = wm + i * 16 + lrow;
                int oa = ra * 128 + (colb ^ ((ra & 7) << 4));
                ah[i] = *(const bf16x8_t*)((const char*)AsH + oa);
                al[i] = *(const bf16x8_t*)((const char*)AsL + oa);
                int rb = wn + i * 16 + lrow;
                int ob = rb * 128 + (colb ^ ((rb & 7) << 4));
                bh[i] = *(const bf16x8_t*)((const char*)BsH + ob);
                bl[i] = *(const bf16x8_t*)((const char*)BsL + ob);
            }
            #pragma unroll
            for (int mi = 0; mi < 2; ++mi)
                #pragma unroll
                for (int ni = 0; ni < 2; ++ni) {
                    acc[mi][ni] = __builtin_amdgcn_mfma_f32_16x16x32_bf16(
                        ah[mi], bh[ni], acc[mi][ni], 0, 0, 0);
                    acc[mi][ni] = __builtin_amdgcn_mfma_f32_16x16x32_bf16(
                        ah[mi], bl[ni], acc[mi][ni], 0, 0, 0);
                    acc[mi][ni] = __builtin_amdgcn_mfma_f32_16x16x32_bf16(
                        al[mi], bh[ni], acc[mi][ni], 0, 0, 0);
                }
        }
        __syncthreads();
    }

    #pragma unroll
    for (int mi = 0; mi < 2; ++mi) {
        #pragma unroll
        for (int ni = 0; ni < 2; ++ni) {
            int col = n0 + wn + ni * 16 + lrow;
            #pragma unroll
            for (int j = 0; j < 4; ++j) {
                int row = m0 + wm + mi * 16 + (lane >> 4) * 4 + j;
                if (row < M) {
                    float v = acc[mi][ni][j] + bias[col];
                    if (RES) v += res[(size_t)row * N + col];
                    C[(size_t)row * N + col] = v;
                }
            }
        }
    }
}

// ---------------- grouped bf16 MFMA GEMM, m97 geometry: 128x128, BK=64, acc[4][4] ----------------
// 4 waves 2x2 over (128 x 128); each wave 64x64. gl_lds, single buffer, 2 barriers.
template<int GATHER, int GELU, int OUT_BF16>
__global__ void mfma_gemm_grouped128(const unsigned short* __restrict__ A,
                                     const unsigned short* __restrict__ Bt,
                                     const float* __restrict__ bias,
                                     const int* __restrict__ offsets,
                                     const int* __restrict__ row2tok,
                                     void* __restrict__ Cout,
                                     const unsigned short* __restrict__ zrow,
                                     int N, int K, int nxb) {
    __shared__ unsigned short As[128 * 64];    // 16 KB, rows of 128B
    __shared__ unsigned short Bs[128 * 64];    // 16 KB
    __shared__ int toks[128];

    int L = xcd_remap(blockIdx.x, gridDim.x);
    int xb = L % nxb;
    int n0 = (L / nxb) * 128;
    int r0 = xb * 128;
    if (r0 >= offsets[8]) return;
    int e = 0;
    while (r0 >= offsets[e + 1]) ++e;

    int tid = threadIdx.x;
    if (GATHER) {
        if (tid < 128) toks[tid] = row2tok[r0 + tid];
        __syncthreads();
    }

    const unsigned short* Be = Bt + (size_t)e * N * K;

    int lane = tid & 63;
    int wid = tid >> 6;
    int wm = (wid >> 1) * 64;
    int wn = (wid & 1) * 64;
    int colb_base = (lane >> 4) * 16;
    int lrow = lane & 15;

    f32x4_t acc[4][4] = {};

    for (int k0 = 0; k0 < K; k0 += 64) {
        // A: 128 rows x 64 el = 1024 slots (4/thread); B same
        #pragma unroll
        for (int p = 0; p < 4; ++p) {
            int s = tid + p * 256;
            int r = s >> 3, c = s & 7;
            int gc = c ^ (r & 7);
            const void* asrc;
            if (GATHER) {
                int tok = toks[r];
                asrc = (tok >= 0) ? (const void*)(A + (size_t)tok * K + k0 + gc * 8)
                                  : (const void*)zrow;
            } else {
                asrc = (const void*)(A + (size_t)(r0 + r) * K + k0 + gc * 8);
            }
            gl_lds16(asrc, (char*)As + s * 16);
            gl_lds16((const void*)(Be + (size_t)(n0 + r) * K + k0 + gc * 8),
                     (char*)Bs + s * 16);
        }
        __syncthreads();
        #pragma unroll
        for (int kk = 0; kk < 2; ++kk) {
            int colb = kk * 64 + colb_base;
            bf16x8_t a[4], b[4];
            #pragma unroll
            for (int i = 0; i < 4; ++i) {
                int ra = wm + i * 16 + lrow;
                a[i] = *(const bf16x8_t*)((const char*)As + ra * 128 + (colb ^ ((ra & 7) << 4)));
                int rb = wn + i * 16 + lrow;
                b[i] = *(const bf16x8_t*)((const char*)Bs + rb * 128 + (colb ^ ((rb & 7) << 4)));
            }
            #pragma unroll
            for (int mi = 0; mi < 4; ++mi)
                #pragma unroll
                for (int ni = 0; ni < 4; ++ni)
                    acc[mi][ni] = __builtin_amdgcn_mfma_f32_16x16x32_bf16(
                        a[mi], b[ni], acc[mi][ni], 0, 0, 0);
        }
        __syncthreads();
    }

    #pragma unroll
    for (int mi = 0; mi < 4; ++mi) {
        #pragma unroll
        for (int ni = 0; ni < 4; ++ni) {
            int col = n0 + wn + ni * 16 + lrow;
            float bv = GELU ? bias[(size_t)e * N + col] : 0.f;
            #pragma unroll
            for (int j = 0; j < 4; ++j) {
                int row = r0 + wm + mi * 16 + (lane >> 4) * 4 + j;
                float v = acc[mi][ni][j] + bv;
                if (GELU) v = 0.5f * v * (1.f + erff(v * 0.70710678f));
                if (OUT_BF16)
                    ((unsigned short*)Cout)[(size_t)row * N + col] = f2bf(v);
                else
                    ((float*)Cout)[(size_t)row * N + col] = v;
            }
        }
    }
}

// ---------------- grouped bf16 MFMA GEMM, 64x128 tile, BK=128 (r17 form, used for e2) ----------------
template<int GATHER, int GELU, int OUT_BF16>
__global__ void mfma_gemm_grouped(const unsigned short* __restrict__ A,
                                  const unsigned short* __restrict__ Bt,
                                  const float* __restrict__ bias,
                                  const int* __restrict__ offsets,
                                  const int* __restrict__ row2tok,
                                  void* __restrict__ Cout,
                                  const unsigned short* __restrict__ zrow,
                                  int N, int K, int nxb) {
    __shared__ unsigned short As[64 * 128];    // 16 KB, rows of 256B
    __shared__ unsigned short Bs[128 * 128];   // 32 KB, rows of 256B
    __shared__ int toks[64];

    int L = xcd_remap(blockIdx.x, gridDim.x);
    int xb = L % nxb;
    int n0 = (L / nxb) * 128;
    int r0 = xb * 64;
    if (r0 >= offsets[8]) return;
    int e = 0;
    while (r0 >= offsets[e + 1]) ++e;

    int tid = threadIdx.x;
    if (GATHER && tid < 64) toks[tid] = row2tok[r0 + tid];
    __syncthreads();

    const unsigned short* Be = Bt + (size_t)e * N * K;

    int lane = tid & 63;
    int wid = tid >> 6;
    int wm = (wid >> 1) * 32;
    int wn = (wid & 1) * 64;
    int colb_base = (lane >> 4) * 16;
    int lrow = lane & 15;

    f32x4_t acc[2][4] = {};

    for (int k0 = 0; k0 < K; k0 += 128) {
        #pragma unroll
        for (int p = 0; p < 4; ++p) {
            int s = tid + p * 256;
            int r = s >> 4, c = s & 15;
            int gc = c ^ (r & 7);
            const void* asrc;
            if (GATHER) {
                int tok = toks[r];
                asrc = (tok >= 0) ? (const void*)(A + (size_t)tok * K + k0 + gc * 8)
                                  : (const void*)zrow;
            } else {
                asrc = (const void*)(A + (size_t)(r0 + r) * K + k0 + gc * 8);
            }
            gl_lds16(asrc, (char*)As + s * 16);
        }
        #pragma unroll
        for (int p = 0; p < 8; ++p) {
            int s = tid + p * 256;
            int r = s >> 4, c = s & 15;
            int gc = c ^ (r & 7);
            gl_lds16((const void*)(Be + (size_t)(n0 + r) * K + k0 + gc * 8),
                     (char*)Bs + s * 16);
        }
        __syncthreads();
        #pragma unroll
        for (int kk = 0; kk < 4; ++kk) {
            int colb = kk * 64 + colb_base;
            bf16x8_t a[2], b[4];
            #pragma unroll
            for (int i = 0; i < 2; ++i) {
                int ra = wm + i * 16 + lrow;
                a[i] = *(const bf16x8_t*)((const char*)As + ra * 256 + (colb ^ ((ra & 7) << 4)));
            }
            #pragma unroll
            for (int i = 0; i < 4; ++i) {
                int rb = wn + i * 16 + lrow;
                b[i] = *(const bf16x8_t*)((const char*)Bs + rb * 256 + (colb ^ ((rb & 7) << 4)));
            }
            #pragma unroll
            for (int mi = 0; mi < 2; ++mi)
                #pragma unroll
                for (int ni = 0; ni < 4; ++ni)
                    acc[mi][ni] = __builtin_amdgcn_mfma_f32_16x16x32_bf16(
                        a[mi], b[ni], acc[mi][ni], 0, 0, 0);
        }
        __syncthreads();
    }

    #pragma unroll
    for (int mi = 0; mi < 2; ++mi) {
        #pragma unroll
        for (int ni = 0; ni < 4; ++ni) {
            int col = n0 + wn + ni * 16 + lrow;
            float bv = GELU ? bias[(size_t)e * N + col] : 0.f;
            #pragma unroll
            for (int j = 0; j < 4; ++j) {
                int row = r0 + wm + mi * 16 + (lane >> 4) * 4 + j;
                float v = acc[mi][ni][j] + bv;
                if (GELU) v = 0.5f * v * (1.f + erff(v * 0.70710678f));
                if (OUT_BF16)
                    ((unsigned short*)Cout)[(size_t)row * N + col] = f2bf(v);
                else
                    ((float*)Cout)[(size_t)row * N + col] = v;
            }
        }
    }
}

// ---------------- combine: out = x_res + sum_k g_k*(y[row_k] + b2[e_k]) ----------------
__global__ void combine_kernel(const float* __restrict__ x_res, const float* __restrict__ y,
                               const float* __restrict__ b2, const int* __restrict__ tok_e,
                               const float* __restrict__ tok_g, const int* __restrict__ tok_row,
                               float* __restrict__ out) {
    int t = blockIdx.x;
    int c = blockIdx.y * 256 + threadIdx.x;
    int e0 = tok_e[t*2], e1 = tok_e[t*2+1];
    float g0 = tok_g[t*2], g1 = tok_g[t*2+1];
    int r0 = tok_row[t*2], r1 = tok_row[t*2+1];
    float v = x_res[(size_t)t * DIMC + c]
            + g0 * (y[(size_t)r0 * DIMC + c] + b2[(size_t)e0 * DIMC + c])
            + g1 * (y[(size_t)r1 * DIMC + c] + b2[(size_t)e1 * DIMC + c]);
    out[(size_t)t * DIMC + c] = v;
}

extern "C" void kernel_launch(void* const* d_in, const int* in_sizes, int n_in,
                              void* d_out, int out_size, void* d_ws, size_t ws_size,
                              hipStream_t stream) {
    const float* x      = (const float*)d_in[0];
    const float* ln1_g  = (const float*)d_in[1];
    const float* ln1_b  = (const float*)d_in[2];
    const float* qkv_w  = (const float*)d_in[3];
    const float* qkv_b  = (const float*)d_in[4];
    const float* proj_w = (const float*)d_in[5];
    const float* proj_b = (const float*)d_in[6];
    const float* ln2_g  = (const float*)d_in[7];
    const float* ln2_b  = (const float*)d_in[8];
    const float* gate_w = (const float*)d_in[9];
    const float* w1     = (const float*)d_in[10];
    const float* b1     = (const float*)d_in[11];
    const float* w2     = (const float*)d_in[12];
    const float* b2     = (const float*)d_in[13];
    float* out = (float*)d_out;

    char* p = (char*)d_ws;
    auto alloc = [&](size_t nbytes) {
        void* r = (void*)p;
        p += (nbytes + 255) & ~(size_t)255;
        return r;
    };
    unsigned short* xn1_h   = (unsigned short*)alloc((size_t)TT * DIMC * 2);
    unsigned short* xn1_l   = (unsigned short*)alloc((size_t)TT * DIMC * 2);
    float*          qkv     = (float*)alloc((size_t)TT * 2304 * 4);
    unsigned short* ao_h    = (unsigned short*)alloc((size_t)TT * DIMC * 2);
    unsigned short* ao_l    = (unsigned short*)alloc((size_t)TT * DIMC * 2);
    float*          x_res   = (float*)alloc((size_t)TT * DIMC * 4);
    unsigned short* xn2_bf  = (unsigned short*)alloc((size_t)TT * DIMC * 2);
    unsigned short* h       = (unsigned short*)alloc((size_t)CAP_ROWS * HID * 2);
    float*          y       = (float*)alloc((size_t)CAP_ROWS * DIMC * 4);
    unsigned short* w1t     = (unsigned short*)alloc((size_t)EXPERTS * DIMC * HID * 2);
    unsigned short* w2t     = (unsigned short*)alloc((size_t)EXPERTS * DIMC * HID * 2);
    unsigned short* qwt_h   = (unsigned short*)alloc((size_t)DIMC * 2304 * 2);
    unsigned short* qwt_l   = (unsigned short*)alloc((size_t)DIMC * 2304 * 2);
    unsigned short* pwt_h   = (unsigned short*)alloc((size_t)DIMC * DIMC * 2);
    unsigned short* pwt_l   = (unsigned short*)alloc((size_t)DIMC * DIMC * 2);
    float*          tok_g   = (float*)alloc((size_t)2 * TT * 4);
    int*            tok_e   = (int*)alloc((size_t)2 * TT * 4);
    int*            tok_row = (int*)alloc((size_t)2 * TT * 4);
    int*            row2tok = (int*)alloc((size_t)CAP_ROWS * 4);
    unsigned short* zrow    = (unsigned short*)alloc(256);
    int*            counts  = (int*)alloc(32 * 4);
    int*            offsets = (int*)alloc(32 * 4);
    int*            cursor  = (int*)alloc(32 * 4);

    init_kernel<<<(CAP_ROWS + 255) / 256, 256, 0, stream>>>(counts, row2tok, CAP_ROWS, zrow);

    // weight transposes (independent of activations)
    transpose_bf16<<<dim3(HID / 64, DIMC / 64, EXPERTS), 256, 0, stream>>>(w1, w1t, DIMC, HID);
    transpose_bf16<<<dim3(DIMC / 64, HID / 64, EXPERTS), 256, 0, stream>>>(w2, w2t, HID, DIMC);
    transpose_split_bf16<<<dim3(2304 / 64, DIMC / 64), 256, 0, stream>>>(qkv_w, qwt_h, qwt_l,
                                                                         DIMC, 2304);
    transpose_split_bf16<<<dim3(DIMC / 64, DIMC / 64), 256, 0, stream>>>(proj_w, pwt_h, pwt_l,
                                                                         DIMC, DIMC);

    ln_kernel_t<0><<<TT, 256, 0, stream>>>(x, ln1_g, ln1_b, xn1_h, xn1_l,
                                           nullptr, nullptr, nullptr, nullptr);

    {
        int nmb = (TT + 63) / 64;                       // 25
        int nwg = nmb * (2304 / 64);                    // 900
        mfma_gemm_split<0><<<nwg, 256, 0, stream>>>(
            xn1_h, xn1_l, qwt_h, qwt_l, qkv_b, nullptr, qkv, zrow, TT, 2304, DIMC, nmb);
    }

    attn_mfma_kernel<<<dim3(BB * HEADS, 4), 512, 0, stream>>>(qkv, ao_h, ao_l);

    {
        int nmb = (TT + 63) / 64;                       // 25
        int nwg = nmb * (DIMC / 64);                    // 300
        mfma_gemm_split<1><<<nwg, 256, 0, stream>>>(
            ao_h, ao_l, pwt_h, pwt_l, proj_b, x, x_res, zrow, TT, DIMC, DIMC, nmb);
    }

    // ln2 with fused gate (logits in fp32, top-2 + softmax + counts)
    ln_kernel_t<1><<<TT, 256, 0, stream>>>(x_res, ln2_g, ln2_b, xn2_bf, nullptr,
                                           gate_w, tok_e, tok_g, counts);

    offsets_kernel<<<1, 64, 0, stream>>>(counts, offsets, cursor);

    fill_kernel<<<(TT + 255) / 256, 256, 0, stream>>>(tok_e, cursor, row2tok, tok_row);

    {
        // e1: m97 geometry 128x128, BK=64
        int nxb1 = CAP_ROWS / 128;                      // 33
        int nwg1 = (HID / 128) * nxb1;                  // 24*33 = 792
        mfma_gemm_grouped128<1, 1, 1><<<nwg1, 256, 0, stream>>>(
            xn2_bf, w1t, b1, offsets, row2tok, h, zrow, HID, DIMC, nxb1);

        // e2: 64x128, BK=128 (r17 form)
        int nxb2 = CAP_ROWS / 64;                       // 66
        int nwg2 = (DIMC / 128) * nxb2;                 // 6*66 = 396
        mfma_gemm_grouped<0, 0, 0><<<nwg2, 256, 0, stream>>>(
            h, w2t, nullptr, offsets, row2tok, y, zrow, DIMC, HID, nxb2);
    }

    combine_kernel<<<dim3(TT, 3), 256, 0, stream>>>(x_res, y, b2, tok_e, tok_g, tok_row, out);
}

// Round 19
// 264.491 us; speedup vs baseline: 1.4271x; 1.0074x over previous
//
#include <hip/hip_runtime.h>
#include <hip/hip_bf16.h>
#include <math.h>

#define DIMC 768
#define HEADS 12
#define HD 64
#define EXPERTS 8
#define HID 3072
#define BB 8
#define NN 196
#define TT (BB*NN)      // 1568
#define CAP_ROWS 4224   // multiple of 128, >= 2*TT + 8*128 headroom
#define LN_EPS 1e-5f

typedef float f32x4_t __attribute__((ext_vector_type(4)));
typedef short bf16x8_t __attribute__((ext_vector_type(8)));
typedef unsigned short u16x8_t __attribute__((ext_vector_type(8)));

__device__ __forceinline__ unsigned short f2bf(float f) {
    unsigned int u = __float_as_uint(f);
    u += 0x7FFFu + ((u >> 16) & 1u);   // round-to-nearest-even
    return (unsigned short)(u >> 16);
}
__device__ __forceinline__ float bf2f(unsigned short u) {
    return __uint_as_float(((unsigned int)u) << 16);
}

// async global->LDS, 16B per lane; LDS dest = wave-uniform base + lane*16 (linear)
__device__ __forceinline__ void gl_lds16(const void* g, void* l) {
    __builtin_amdgcn_global_load_lds(
        (const __attribute__((address_space(1))) unsigned int*)g,
        (__attribute__((address_space(3))) unsigned int*)l, 16, 0, 0);
}

// bijective XCD-chunked remap (m204): physical bid -> logical L
__device__ __forceinline__ int xcd_remap(int pbid, int nwg) {
    int q = nwg >> 3, r8 = nwg & 7;
    int xcd = pbid & 7, slot = pbid >> 3;
    return (xcd < r8) ? xcd * (q + 1) + slot
                      : r8 * (q + 1) + (xcd - r8) * q + slot;
}

// ---------------- LayerNorm (+ optional fused gate): one block per token, 256 threads ----------------
// Wave-shuffle reductions: 2 barriers total (vs 16 LDS-tree) — latency fix, same fp32 math class.
template<int GATE>
__global__ void ln_kernel_t(const float* __restrict__ x, const float* __restrict__ g,
                            const float* __restrict__ b,
                            unsigned short* __restrict__ out_hi,
                            unsigned short* __restrict__ out_lo,
                            const float* __restrict__ gw, int* __restrict__ tok_e,
                            float* __restrict__ tok_g, int* __restrict__ counts) {
    int t = blockIdx.x;
    const float* xr = x + (size_t)t * DIMC;
    int tid = threadIdx.x;
    int lane = tid & 63, w = tid >> 6;
    float v0 = xr[tid], v1 = xr[tid + 256], v2 = xr[tid + 512];
    __shared__ float ws[4], vs[4];

    float s = v0 + v1 + v2;
    #pragma unroll
    for (int off = 32; off > 0; off >>= 1) s += __shfl_xor(s, off, 64);
    if (lane == 0) ws[w] = s;
    __syncthreads();
    float mu = (ws[0] + ws[1] + ws[2] + ws[3]) * (1.0f / DIMC);

    float d0 = v0 - mu, d1 = v1 - mu, d2 = v2 - mu;
    float q = d0 * d0 + d1 * d1 + d2 * d2;
    #pragma unroll
    for (int off = 32; off > 0; off >>= 1) q += __shfl_xor(q, off, 64);
    if (lane == 0) vs[w] = q;
    __syncthreads();
    float rstd = rsqrtf((vs[0] + vs[1] + vs[2] + vs[3]) * (1.0f / DIMC) + LN_EPS);

    float o0 = d0 * rstd * g[tid]       + b[tid];
    float o1 = d1 * rstd * g[tid + 256] + b[tid + 256];
    float o2 = d2 * rstd * g[tid + 512] + b[tid + 512];
    {
        unsigned short* o = out_hi + (size_t)t * DIMC;
        unsigned short h0 = f2bf(o0), h1 = f2bf(o1), h2 = f2bf(o2);
        o[tid] = h0; o[tid + 256] = h1; o[tid + 512] = h2;
        if (out_lo) {
            unsigned short* ol = out_lo + (size_t)t * DIMC;
            ol[tid]       = f2bf(o0 - bf2f(h0));
            ol[tid + 256] = f2bf(o1 - bf2f(h1));
            ol[tid + 512] = f2bf(o2 - bf2f(h2));
        }
    }
    if (GATE) {
        float p[8];
        const float* g0r = gw + (size_t)tid * 8;
        const float* g1r = gw + ((size_t)tid + 256) * 8;
        const float* g2r = gw + ((size_t)tid + 512) * 8;
        #pragma unroll
        for (int e = 0; e < 8; ++e)
            p[e] = o0 * g0r[e] + o1 * g1r[e] + o2 * g2r[e];
        #pragma unroll
        for (int off = 32; off > 0; off >>= 1)
            #pragma unroll
            for (int e = 0; e < 8; ++e) p[e] += __shfl_xor(p[e], off, 64);
        __shared__ float redw[4][8];
        if (lane == 0) {
            #pragma unroll
            for (int e = 0; e < 8; ++e) redw[w][e] = p[e];
        }
        __syncthreads();
        if (tid == 0) {
            float lg[8];
            #pragma unroll
            for (int e = 0; e < 8; ++e)
                lg[e] = redw[0][e] + redw[1][e] + redw[2][e] + redw[3][e];
            int e0 = 0; float l0 = lg[0];
            #pragma unroll
            for (int e = 1; e < 8; ++e) if (lg[e] > l0) { l0 = lg[e]; e0 = e; }
            int e1 = -1; float l1 = -3e38f;
            #pragma unroll
            for (int e = 0; e < 8; ++e) if (e != e0 && lg[e] > l1) { l1 = lg[e]; e1 = e; }
            float pp = expf(l1 - l0);
            float ga = 1.f / (1.f + pp);
            float gb = pp / (1.f + pp);
            tok_e[t*2] = e0; tok_e[t*2+1] = e1;
            tok_g[t*2] = ga; tok_g[t*2+1] = gb;
            atomicAdd(&counts[e0], 1);
            atomicAdd(&counts[e1], 1);
        }
    }
}

// ---------------- MFMA attention, split-precision, 512 threads / 8 waves (validated r11) ----------------
__global__ void attn_mfma_kernel(const float* __restrict__ qkv,
                                 unsigned short* __restrict__ ao_h,
                                 unsigned short* __restrict__ ao_l) {
    __shared__ char psb[64 * 896];                         // 56 KB, swizzled fp32 [64][224]
    __shared__ unsigned short QsH[64 * 64], QsL[64 * 64];
    __shared__ unsigned short KsH[64 * 64], KsL[64 * 64];

    int bh = blockIdx.x;
    int b = bh / HEADS, h = bh % HEADS;
    int q0 = blockIdx.y * 64;
    const float* base = qkv + (size_t)b * NN * 2304 + h * 64;

    int tid = threadIdx.x;                 // 0..511
    int sr = tid >> 3, sq = tid & 7;
    int lane = tid & 63;
    int wid = tid >> 6;
    int wm = (wid >> 2) * 32;
    int wn = (wid & 3) * 16;
    int lrow = lane & 15;
    int lq = lane >> 4;
    int colb_base = lq * 16;

    {
        int r = sr;
        int n = q0 + r;
        float v[8] = {0.f,0.f,0.f,0.f,0.f,0.f,0.f,0.f};
        if (n < NN) {
            float4 a0 = *(const float4*)(base + (size_t)n * 2304 + sq * 8);
            float4 a1 = *(const float4*)(base + (size_t)n * 2304 + sq * 8 + 4);
            v[0]=a0.x; v[1]=a0.y; v[2]=a0.z; v[3]=a0.w;
            v[4]=a1.x; v[5]=a1.y; v[6]=a1.z; v[7]=a1.w;
        }
        u16x8_t hv, lv;
        #pragma unroll
        for (int t = 0; t < 8; ++t) {
            unsigned short hh = f2bf(v[t]);
            hv[t] = hh; lv[t] = f2bf(v[t] - bf2f(hh));
        }
        int off = r * 128 + ((sq * 16) ^ ((r & 7) << 4));
        *(u16x8_t*)((char*)QsH + off) = hv;
        *(u16x8_t*)((char*)QsL + off) = lv;
    }

    for (int kt = 0; kt < 4; ++kt) {
        int j0 = kt * 64;
        __syncthreads();
        {
            int r = sr;
            int n = j0 + r;
            float v[8] = {0.f,0.f,0.f,0.f,0.f,0.f,0.f,0.f};
            if (n < NN) {
                float4 a0 = *(const float4*)(base + (size_t)n * 2304 + 768 + sq * 8);
                float4 a1 = *(const float4*)(base + (size_t)n * 2304 + 768 + sq * 8 + 4);
                v[0]=a0.x; v[1]=a0.y; v[2]=a0.z; v[3]=a0.w;
                v[4]=a1.x; v[5]=a1.y; v[6]=a1.z; v[7]=a1.w;
            }
            u16x8_t hv, lv;
            #pragma unroll
            for (int t = 0; t < 8; ++t) {
                unsigned short hh = f2bf(v[t]);
                hv[t] = hh; lv[t] = f2bf(v[t] - bf2f(hh));
            }
            int off = r * 128 + ((sq * 16) ^ ((r & 7) << 4));
            *(u16x8_t*)((char*)KsH + off) = hv;
            *(u16x8_t*)((char*)KsL + off) = lv;
        }
        __syncthreads();

        f32x4_t acc[2] = {};
        #pragma unroll
        for (int kk = 0; kk < 2; ++kk) {
            int colb = kk * 64 + colb_base;
            bf16x8_t qh[2], ql[2], kh, kl;
            #pragma unroll
            for (int i = 0; i < 2; ++i) {
                int ra = wm + i * 16 + lrow;
                int oa = ra * 128 + (colb ^ ((ra & 7) << 4));
                qh[i] = *(const bf16x8_t*)((const char*)QsH + oa);
                ql[i] = *(const bf16x8_t*)((const char*)QsL + oa);
            }
            int rb = wn + lrow;
            int ob = rb * 128 + (colb ^ ((rb & 7) << 4));
            kh = *(const bf16x8_t*)((const char*)KsH + ob);
            kl = *(const bf16x8_t*)((const char*)KsL + ob);
            #pragma unroll
            for (int mi = 0; mi < 2; ++mi) {
                acc[mi] = __builtin_amdgcn_mfma_f32_16x16x32_bf16(qh[mi], kh, acc[mi], 0, 0, 0);
                acc[mi] = __builtin_amdgcn_mfma_f32_16x16x32_bf16(qh[mi], kl, acc[mi], 0, 0, 0);
                acc[mi] = __builtin_amdgcn_mfma_f32_16x16x32_bf16(ql[mi], kh, acc[mi], 0, 0, 0);
            }
        }
        int jc = j0 + wn + lrow;
        if (jc < 224) {
            #pragma unroll
            for (int mi = 0; mi < 2; ++mi) {
                #pragma unroll
                for (int j = 0; j < 4; ++j) {
                    int row = wm + mi * 16 + lq * 4 + j;
                    int s = (row & 7) ^ (row >> 3);
                    *(float*)(psb + row * 896 + ((jc * 4) ^ (s << 4))) = acc[mi][j] * 0.125f;
                }
            }
        }
    }
    __syncthreads();

    {
        int i = tid >> 3, l = tid & 7;
        int s = (i & 7) ^ (i >> 3);
        char* prow = psb + i * 896;
        float mx = -1e30f;
        for (int j = l; j < NN; j += 8) mx = fmaxf(mx, *(const float*)(prow + ((j * 4) ^ (s << 4))));
        mx = fmaxf(mx, __shfl_xor(mx, 1, 8));
        mx = fmaxf(mx, __shfl_xor(mx, 2, 8));
        mx = fmaxf(mx, __shfl_xor(mx, 4, 8));
        float sum = 0.f;
        for (int j = l; j < NN; j += 8) {
            float* pp = (float*)(prow + ((j * 4) ^ (s << 4)));
            float e = expf(*pp - mx); *pp = e; sum += e;
        }
        sum += __shfl_xor(sum, 1, 8);
        sum += __shfl_xor(sum, 2, 8);
        sum += __shfl_xor(sum, 4, 8);
        float inv = 1.f / sum;
        for (int j = l; j < NN; j += 8) {
            float* pp = (float*)(prow + ((j * 4) ^ (s << 4)));
            *pp *= inv;
        }
    }

    f32x4_t oacc[2] = {};
    for (int kt = 0; kt < 4; ++kt) {
        int j0 = kt * 64;
        __syncthreads();
        {
            int r = sr;
            int n = j0 + r;
            float v[8] = {0.f,0.f,0.f,0.f,0.f,0.f,0.f,0.f};
            if (n < NN) {
                float4 a0 = *(const float4*)(base + (size_t)n * 2304 + 1536 + sq * 8);
                float4 a1 = *(const float4*)(base + (size_t)n * 2304 + 1536 + sq * 8 + 4);
                v[0]=a0.x; v[1]=a0.y; v[2]=a0.z; v[3]=a0.w;
                v[4]=a1.x; v[5]=a1.y; v[6]=a1.z; v[7]=a1.w;
            }
            #pragma unroll
            for (int t = 0; t < 8; ++t) {
                int d = sq * 8 + t;
                int sw = ((d & 7) ^ (d >> 3)) << 4;
                unsigned short hh = f2bf(v[t]);
                int off = d * 128 + ((r * 2) ^ sw);
                *(unsigned short*)((char*)KsH + off) = hh;
                *(unsigned short*)((char*)KsL + off) = f2bf(v[t] - bf2f(hh));
            }
        }
        __syncthreads();

        int kkmax = (kt == 3) ? 1 : 2;
        for (int kk = 0; kk < kkmax; ++kk) {
            int colb = kk * 64 + colb_base;
            bf16x8_t pah[2], pal[2], vh, vl;
            #pragma unroll
            for (int i = 0; i < 2; ++i) {
                int ra = wm + i * 16 + lrow;
                int s = (ra & 7) ^ (ra >> 3);
                const char* prow = psb + ra * 896;
                int jb = (j0 + kk * 32 + lq * 8) * 4;
                float4 a0 = *(const float4*)(prow + (jb ^ (s << 4)));
                float4 a1 = *(const float4*)(prow + ((jb + 16) ^ (s << 4)));
                float vv[8] = {a0.x,a0.y,a0.z,a0.w,a1.x,a1.y,a1.z,a1.w};
                u16x8_t hv, lv;
                #pragma unroll
                for (int t = 0; t < 8; ++t) {
                    unsigned short hh = f2bf(vv[t]);
                    hv[t] = hh; lv[t] = f2bf(vv[t] - bf2f(hh));
                }
                pah[i] = *(bf16x8_t*)&hv;
                pal[i] = *(bf16x8_t*)&lv;
            }
            int rb = wn + lrow;
            int ob = rb * 128 + (colb ^ (((rb & 7) ^ (rb >> 3)) << 4));
            vh = *(const bf16x8_t*)((const char*)KsH + ob);
            vl = *(const bf16x8_t*)((const char*)KsL + ob);
            #pragma unroll
            for (int mi = 0; mi < 2; ++mi) {
                oacc[mi] = __builtin_amdgcn_mfma_f32_16x16x32_bf16(pah[mi], vh, oacc[mi], 0, 0, 0);
                oacc[mi] = __builtin_amdgcn_mfma_f32_16x16x32_bf16(pah[mi], vl, oacc[mi], 0, 0, 0);
                oacc[mi] = __builtin_amdgcn_mfma_f32_16x16x32_bf16(pal[mi], vh, oacc[mi], 0, 0, 0);
            }
        }
    }

    #pragma unroll
    for (int mi = 0; mi < 2; ++mi) {
        int col = h * 64 + wn + lrow;
        #pragma unroll
        for (int j = 0; j < 4; ++j) {
            int n = q0 + wm + mi * 16 + lq * 4 + j;
            if (n < NN) {
                float v = oacc[mi][j];
                unsigned short hh = f2bf(v);
                size_t o = (size_t)(b * NN + n) * DIMC + col;
                ao_h[o] = hh;
                ao_l[o] = f2bf(v - bf2f(hh));
            }
        }
    }
}

__global__ void init_kernel(int* __restrict__ counts, int* __restrict__ row2tok, int cap,
                            unsigned short* __restrict__ zrow) {
    int i = blockIdx.x * blockDim.x + threadIdx.x;
    if (i < 8) counts[i] = 0;
    if (i < 128) zrow[i] = 0;
    if (i < cap) row2tok[i] = -1;
}

__global__ void offsets_kernel(const int* __restrict__ counts, int* __restrict__ offsets,
                               int* __restrict__ cursor) {
    if (threadIdx.x == 0 && blockIdx.x == 0) {
        int off = 0;
        for (int e = 0; e < 8; ++e) {
            offsets[e] = off;
            cursor[e]  = off;
            off += ((counts[e] + 127) / 128) * 128;  // pad each segment to BM=128 (e1 tile)
        }
        offsets[8] = off;
    }
}

__global__ void fill_kernel(const int* __restrict__ tok_e, int* __restrict__ cursor,
                            int* __restrict__ row2tok, int* __restrict__ tok_row) {
    int t = blockIdx.x * blockDim.x + threadIdx.x;
    if (t >= TT) return;
    #pragma unroll
    for (int k = 0; k < 2; ++k) {
        int e = tok_e[t*2+k];
        int slot = atomicAdd(&cursor[e], 1);
        row2tok[slot] = t;
        tok_row[t*2+k] = slot;
    }
}

// ---------------- batched transpose + fp32->bf16: src [B][R][C] -> dst [B][C][R] ----------------
__global__ void transpose_bf16(const float* __restrict__ src, unsigned short* __restrict__ dst,
                               int R, int C) {
    __shared__ float tile[64][65];
    const float* s = src + (size_t)blockIdx.z * R * C;
    unsigned short* d = dst + (size_t)blockIdx.z * R * C;
    int c0 = blockIdx.x * 64, r0 = blockIdx.y * 64;
    int tid = threadIdx.x;
    int tr = tid >> 4;
    int tc = (tid & 15) * 4;
    #pragma unroll
    for (int p = 0; p < 4; ++p) {
        int r = tr + p * 16;
        const float4 v = *(const float4*)(s + (size_t)(r0 + r) * C + c0 + tc);
        tile[r][tc+0] = v.x; tile[r][tc+1] = v.y; tile[r][tc+2] = v.z; tile[r][tc+3] = v.w;
    }
    __syncthreads();
    #pragma unroll
    for (int p = 0; p < 4; ++p) {
        int c = tr + p * 16;
        ushort4 o;
        o.x = f2bf(tile[tc+0][c]);
        o.y = f2bf(tile[tc+1][c]);
        o.z = f2bf(tile[tc+2][c]);
        o.w = f2bf(tile[tc+3][c]);
        *(ushort4*)(d + (size_t)(c0 + c) * R + r0 + tc) = o;
    }
}

// ---------------- transpose + hi/lo split: src [R][C] fp32 -> dh/dl [C][R] bf16 ----------------
__global__ void transpose_split_bf16(const float* __restrict__ src,
                                     unsigned short* __restrict__ dh,
                                     unsigned short* __restrict__ dl, int R, int C) {
    __shared__ float tile[64][65];
    int c0 = blockIdx.x * 64, r0 = blockIdx.y * 64;
    int tid = threadIdx.x;
    int tr = tid >> 4;
    int tc = (tid & 15) * 4;
    #pragma unroll
    for (int p = 0; p < 4; ++p) {
        int r = tr + p * 16;
        const float4 v = *(const float4*)(src + (size_t)(r0 + r) * C + c0 + tc);
        tile[r][tc+0] = v.x; tile[r][tc+1] = v.y; tile[r][tc+2] = v.z; tile[r][tc+3] = v.w;
    }
    __syncthreads();
    #pragma unroll
    for (int p = 0; p < 4; ++p) {
        int c = tr + p * 16;
        ushort4 h, l;
        float v0 = tile[tc+0][c], v1 = tile[tc+1][c], v2 = tile[tc+2][c], v3 = tile[tc+3][c];
        h.x = f2bf(v0); l.x = f2bf(v0 - bf2f(h.x));
        h.y = f2bf(v1); l.y = f2bf(v1 - bf2f(h.y));
        h.z = f2bf(v2); l.z = f2bf(v2 - bf2f(h.z));
        h.w = f2bf(v3); l.w = f2bf(v3 - bf2f(h.w));
        size_t off = (size_t)(c0 + c) * R + r0 + tc;
        *(ushort4*)(dh + off) = h;
        *(ushort4*)(dl + off) = l;
    }
}

// ---------------- split-precision MFMA GEMM, gl_lds staging + XCD remap (validated r15-r18) ----------------
template<int RES>
__global__ void mfma_gemm_split(const unsigned short* __restrict__ Ah,
                                const unsigned short* __restrict__ Al,
                                const unsigned short* __restrict__ Bth,
                                const unsigned short* __restrict__ Btl,
                                const float* __restrict__ bias,
                                const float* __restrict__ res,
                                float* __restrict__ C,
                                const unsigned short* __restrict__ zrow,
                                int M, int N, int K, int nmb) {
    __shared__ unsigned short AsH[64 * 64];
    __shared__ unsigned short AsL[64 * 64];
    __shared__ unsigned short BsH[64 * 64];
    __shared__ unsigned short BsL[64 * 64];

    int L = xcd_remap(blockIdx.x, gridDim.x);
    int m0 = (L % nmb) * 64;
    int n0 = (L / nmb) * 64;
    int tid = threadIdx.x;
    int lane = tid & 63;
    int wid = tid >> 6;
    int wm = (wid >> 1) * 32;
    int wn = (wid & 1) * 32;
    int colb_base = (lane >> 4) * 16;
    int lrow = lane & 15;

    f32x4_t acc[2][2] = {};

    for (int k0 = 0; k0 < K; k0 += 64) {
        #pragma unroll
        for (int p = 0; p < 2; ++p) {
            int s = tid + p * 256;         // slot 0..511
            int r = s >> 3, c = s & 7;
            int gc = c ^ (r & 7);          // pre-swizzled source chunk
            bool inM = (m0 + r < M);
            size_t aoff = (size_t)(m0 + r) * K + k0 + gc * 8;
            gl_lds16(inM ? (const void*)(Ah + aoff) : (const void*)zrow, (char*)AsH + s * 16);
            gl_lds16(inM ? (const void*)(Al + aoff) : (const void*)zrow, (char*)AsL + s * 16);
            size_t boff = (size_t)(n0 + r) * K + k0 + gc * 8;
            gl_lds16((const void*)(Bth + boff), (char*)BsH + s * 16);
            gl_lds16((const void*)(Btl + boff), (char*)BsL + s * 16);
        }
        __syncthreads();
        #pragma unroll
        for (int kk = 0; kk < 2; ++kk) {
            int colb = kk * 64 + colb_base;
            bf16x8_t ah[2], al[2], bh[2], bl[2];
            #pragma unroll
            for (int i = 0; i < 2; ++i) {
                int ra = wm + i * 16 + lrow;
                int oa = ra * 128 + (colb ^ ((ra & 7) << 4));
                ah[i] = *(const bf16x8_t*)((const char*)AsH + oa);
                al[i] = *(const bf16x8_t*)((const char*)AsL + oa);
                int rb = wn + i * 16 + lrow;
                int ob = rb * 128 + (colb ^ ((rb & 7) << 4));
                bh[i] = *(const bf16x8_t*)((const char*)BsH + ob);
                bl[i] = *(const bf16x8_t*)((const char*)BsL + ob);
            }
            #pragma unroll
            for (int mi = 0; mi < 2; ++mi)
                #pragma unroll
                for (int ni = 0; ni < 2; ++ni) {
                    acc[mi][ni] = __builtin_amdgcn_mfma_f32_16x16x32_bf16(
                        ah[mi], bh[ni], acc[mi][ni], 0, 0, 0);
                    acc[mi][ni] = __builtin_amdgcn_mfma_f32_16x16x32_bf16(
                        ah[mi], bl[ni], acc[mi][ni], 0, 0, 0);
                    acc[mi][ni] = __builtin_amdgcn_mfma_f32_16x16x32_bf16(
                        al[mi], bh[ni], acc[mi][ni], 0, 0, 0);
                }
        }
        __syncthreads();
    }

    #pragma unroll
    for (int mi = 0; mi < 2; ++mi) {
        #pragma unroll
        for (int ni = 0; ni < 2; ++ni) {
            int col = n0 + wn + ni * 16 + lrow;
            #pragma unroll
            for (int j = 0; j < 4; ++j) {
                int row = m0 + wm + mi * 16 + (lane >> 4) * 4 + j;
                if (row < M) {
                    float v = acc[mi][ni][j] + bias[col];
                    if (RES) v += res[(size_t)row * N + col];
                    C[(size_t)row * N + col] = v;
                }
            }
        }
    }
}

// ---------------- grouped bf16 MFMA GEMM, m97 geometry: 128x128, BK=64, acc[4][4] (validated r18) ----------------
template<int GATHER, int GELU, int OUT_BF16>
__global__ void mfma_gemm_grouped128(const unsigned short* __restrict__ A,
                                     const unsigned short* __restrict__ Bt,
                                     const float* __restrict__ bias,
                                     const int* __restrict__ offsets,
                                     const int* __restrict__ row2tok,
                                     void* __restrict__ Cout,
                                     const unsigned short* __restrict__ zrow,
                                     int N, int K, int nxb) {
    __shared__ unsigned short As[128 * 64];    // 16 KB, rows of 128B
    __shared__ unsigned short Bs[128 * 64];    // 16 KB
    __shared__ int toks[128];

    int L = xcd_remap(blockIdx.x, gridDim.x);
    int xb = L % nxb;
    int n0 = (L / nxb) * 128;
    int r0 = xb * 128;
    if (r0 >= offsets[8]) return;
    int e = 0;
    while (r0 >= offsets[e + 1]) ++e;

    int tid = threadIdx.x;
    if (GATHER) {
        if (tid < 128) toks[tid] = row2tok[r0 + tid];
        __syncthreads();
    }

    const unsigned short* Be = Bt + (size_t)e * N * K;

    int lane = tid & 63;
    int wid = tid >> 6;
    int wm = (wid >> 1) * 64;
    int wn = (wid & 1) * 64;
    int colb_base = (lane >> 4) * 16;
    int lrow = lane & 15;

    f32x4_t acc[4][4] = {};

    for (int k0 = 0; k0 < K; k0 += 64) {
        #pragma unroll
        for (int p = 0; p < 4; ++p) {
            int s = tid + p * 256;
            int r = s >> 3, c = s & 7;
            int gc = c ^ (r & 7);
            const void* asrc;
            if (GATHER) {
                int tok = toks[r];
                asrc = (tok >= 0) ? (const void*)(A + (size_t)tok * K + k0 + gc * 8)
                                  : (const void*)zrow;
            } else {
                asrc = (const void*)(A + (size_t)(r0 + r) * K + k0 + gc * 8);
            }
            gl_lds16(asrc, (char*)As + s * 16);
            gl_lds16((const void*)(Be + (size_t)(n0 + r) * K + k0 + gc * 8),
                     (char*)Bs + s * 16);
        }
        __syncthreads();
        #pragma unroll
        for (int kk = 0; kk < 2; ++kk) {
            int colb = kk * 64 + colb_base;
            bf16x8_t a[4], b[4];
            #pragma unroll
            for (int i = 0; i < 4; ++i) {
                int ra = wm + i * 16 + lrow;
                a[i] = *(const bf16x8_t*)((const char*)As + ra * 128 + (colb ^ ((ra & 7) << 4)));
                int rb = wn + i * 16 + lrow;
                b[i] = *(const bf16x8_t*)((const char*)Bs + rb * 128 + (colb ^ ((rb & 7) << 4)));
            }
            #pragma unroll
            for (int mi = 0; mi < 4; ++mi)
                #pragma unroll
                for (int ni = 0; ni < 4; ++ni)
                    acc[mi][ni] = __builtin_amdgcn_mfma_f32_16x16x32_bf16(
                        a[mi], b[ni], acc[mi][ni], 0, 0, 0);
        }
        __syncthreads();
    }

    #pragma unroll
    for (int mi = 0; mi < 4; ++mi) {
        #pragma unroll
        for (int ni = 0; ni < 4; ++ni) {
            int col = n0 + wn + ni * 16 + lrow;
            float bv = GELU ? bias[(size_t)e * N + col] : 0.f;
            #pragma unroll
            for (int j = 0; j < 4; ++j) {
                int row = r0 + wm + mi * 16 + (lane >> 4) * 4 + j;
                float v = acc[mi][ni][j] + bv;
                if (GELU) v = 0.5f * v * (1.f + erff(v * 0.70710678f));
                if (OUT_BF16)
                    ((unsigned short*)Cout)[(size_t)row * N + col] = f2bf(v);
                else
                    ((float*)Cout)[(size_t)row * N + col] = v;
            }
        }
    }
}

// ---------------- grouped bf16 MFMA GEMM, 64x128 tile, BK=128 (r17 form, used for e2) ----------------
template<int GATHER, int GELU, int OUT_BF16>
__global__ void mfma_gemm_grouped(const unsigned short* __restrict__ A,
                                  const unsigned short* __restrict__ Bt,
                                  const float* __restrict__ bias,
                                  const int* __restrict__ offsets,
                                  const int* __restrict__ row2tok,
                                  void* __restrict__ Cout,
                                  const unsigned short* __restrict__ zrow,
                                  int N, int K, int nxb) {
    __shared__ unsigned short As[64 * 128];    // 16 KB, rows of 256B
    __shared__ unsigned short Bs[128 * 128];   // 32 KB, rows of 256B
    __shared__ int toks[64];

    int L = xcd_remap(blockIdx.x, gridDim.x);
    int xb = L % nxb;
    int n0 = (L / nxb) * 128;
    int r0 = xb * 64;
    if (r0 >= offsets[8]) return;
    int e = 0;
    while (r0 >= offsets[e + 1]) ++e;

    int tid = threadIdx.x;
    if (GATHER && tid < 64) toks[tid] = row2tok[r0 + tid];
    __syncthreads();

    const unsigned short* Be = Bt + (size_t)e * N * K;

    int lane = tid & 63;
    int wid = tid >> 6;
    int wm = (wid >> 1) * 32;
    int wn = (wid & 1) * 64;
    int colb_base = (lane >> 4) * 16;
    int lrow = lane & 15;

    f32x4_t acc[2][4] = {};

    for (int k0 = 0; k0 < K; k0 += 128) {
        #pragma unroll
        for (int p = 0; p < 4; ++p) {
            int s = tid + p * 256;
            int r = s >> 4, c = s & 15;
            int gc = c ^ (r & 7);
            const void* asrc;
            if (GATHER) {
                int tok = toks[r];
                asrc = (tok >= 0) ? (const void*)(A + (size_t)tok * K + k0 + gc * 8)
                                  : (const void*)zrow;
            } else {
                asrc = (const void*)(A + (size_t)(r0 + r) * K + k0 + gc * 8);
            }
            gl_lds16(asrc, (char*)As + s * 16);
        }
        #pragma unroll
        for (int p = 0; p < 8; ++p) {
            int s = tid + p * 256;
            int r = s >> 4, c = s & 15;
            int gc = c ^ (r & 7);
            gl_lds16((const void*)(Be + (size_t)(n0 + r) * K + k0 + gc * 8),
                     (char*)Bs + s * 16);
        }
        __syncthreads();
        #pragma unroll
        for (int kk = 0; kk < 4; ++kk) {
            int colb = kk * 64 + colb_base;
            bf16x8_t a[2], b[4];
            #pragma unroll
            for (int i = 0; i < 2; ++i) {
                int ra = wm + i * 16 + lrow;
                a[i] = *(const bf16x8_t*)((const char*)As + ra * 256 + (colb ^ ((ra & 7) << 4)));
            }
            #pragma unroll
            for (int i = 0; i < 4; ++i) {
                int rb = wn + i * 16 + lrow;
                b[i] = *(const bf16x8_t*)((const char*)Bs + rb * 256 + (colb ^ ((rb & 7) << 4)));
            }
            #pragma unroll
            for (int mi = 0; mi < 2; ++mi)
                #pragma unroll
                for (int ni = 0; ni < 4; ++ni)
                    acc[mi][ni] = __builtin_amdgcn_mfma_f32_16x16x32_bf16(
                        a[mi], b[ni], acc[mi][ni], 0, 0, 0);
        }
        __syncthreads();
    }

    #pragma unroll
    for (int mi = 0; mi < 2; ++mi) {
        #pragma unroll
        for (int ni = 0; ni < 4; ++ni) {
            int col = n0 + wn + ni * 16 + lrow;
            float bv = GELU ? bias[(size_t)e * N + col] : 0.f;
            #pragma unroll
            for (int j = 0; j < 4; ++j) {
                int row = r0 + wm + mi * 16 + (lane >> 4) * 4 + j;
                float v = acc[mi][ni][j] + bv;
                if (GELU) v = 0.5f * v * (1.f + erff(v * 0.70710678f));
                if (OUT_BF16)
                    ((unsigned short*)Cout)[(size_t)row * N + col] = f2bf(v);
                else
                    ((float*)Cout)[(size_t)row * N + col] = v;
            }
        }
    }
}

// ---------------- combine: out = x_res + sum_k g_k*(y[row_k] + b2[e_k]) ----------------
__global__ void combine_kernel(const float* __restrict__ x_res, const float* __restrict__ y,
                               const float* __restrict__ b2, const int* __restrict__ tok_e,
                               const float* __restrict__ tok_g, const int* __restrict__ tok_row,
                               float* __restrict__ out) {
    int t = blockIdx.x;
    int c = blockIdx.y * 256 + threadIdx.x;
    int e0 = tok_e[t*2], e1 = tok_e[t*2+1];
    float g0 = tok_g[t*2], g1 = tok_g[t*2+1];
    int r0 = tok_row[t*2], r1 = tok_row[t*2+1];
    float v = x_res[(size_t)t * DIMC + c]
            + g0 * (y[(size_t)r0 * DIMC + c] + b2[(size_t)e0 * DIMC + c])
            + g1 * (y[(size_t)r1 * DIMC + c] + b2[(size_t)e1 * DIMC + c]);
    out[(size_t)t * DIMC + c] = v;
}

extern "C" void kernel_launch(void* const* d_in, const int* in_sizes, int n_in,
                              void* d_out, int out_size, void* d_ws, size_t ws_size,
                              hipStream_t stream) {
    const float* x      = (const float*)d_in[0];
    const float* ln1_g  = (const float*)d_in[1];
    const float* ln1_b  = (const float*)d_in[2];
    const float* qkv_w  = (const float*)d_in[3];
    const float* qkv_b  = (const float*)d_in[4];
    const float* proj_w = (const float*)d_in[5];
    const float* proj_b = (const float*)d_in[6];
    const float* ln2_g  = (const float*)d_in[7];
    const float* ln2_b  = (const float*)d_in[8];
    const float* gate_w = (const float*)d_in[9];
    const float* w1     = (const float*)d_in[10];
    const float* b1     = (const float*)d_in[11];
    const float* w2     = (const float*)d_in[12];
    const float* b2     = (const float*)d_in[13];
    float* out = (float*)d_out;

    char* p = (char*)d_ws;
    auto alloc = [&](size_t nbytes) {
        void* r = (void*)p;
        p += (nbytes + 255) & ~(size_t)255;
        return r;
    };
    unsigned short* xn1_h   = (unsigned short*)alloc((size_t)TT * DIMC * 2);
    unsigned short* xn1_l   = (unsigned short*)alloc((size_t)TT * DIMC * 2);
    float*          qkv     = (float*)alloc((size_t)TT * 2304 * 4);
    unsigned short* ao_h    = (unsigned short*)alloc((size_t)TT * DIMC * 2);
    unsigned short* ao_l    = (unsigned short*)alloc((size_t)TT * DIMC * 2);
    float*          x_res   = (float*)alloc((size_t)TT * DIMC * 4);
    unsigned short* xn2_bf  = (unsigned short*)alloc((size_t)TT * DIMC * 2);
    unsigned short* h       = (unsigned short*)alloc((size_t)CAP_ROWS * HID * 2);
    float*          y       = (float*)alloc((size_t)CAP_ROWS * DIMC * 4);
    unsigned short* w1t     = (unsigned short*)alloc((size_t)EXPERTS * DIMC * HID * 2);
    unsigned short* w2t     = (unsigned short*)alloc((size_t)EXPERTS * DIMC * HID * 2);
    unsigned short* qwt_h   = (unsigned short*)alloc((size_t)DIMC * 2304 * 2);
    unsigned short* qwt_l   = (unsigned short*)alloc((size_t)DIMC * 2304 * 2);
    unsigned short* pwt_h   = (unsigned short*)alloc((size_t)DIMC * DIMC * 2);
    unsigned short* pwt_l   = (unsigned short*)alloc((size_t)DIMC * DIMC * 2);
    float*          tok_g   = (float*)alloc((size_t)2 * TT * 4);
    int*            tok_e   = (int*)alloc((size_t)2 * TT * 4);
    int*            tok_row = (int*)alloc((size_t)2 * TT * 4);
    int*            row2tok = (int*)alloc((size_t)CAP_ROWS * 4);
    unsigned short* zrow    = (unsigned short*)alloc(256);
    int*            counts  = (int*)alloc(32 * 4);
    int*            offsets = (int*)alloc(32 * 4);
    int*            cursor  = (int*)alloc(32 * 4);

    init_kernel<<<(CAP_ROWS + 255) / 256, 256, 0, stream>>>(counts, row2tok, CAP_ROWS, zrow);

    // weight transposes (independent of activations)
    transpose_bf16<<<dim3(HID / 64, DIMC / 64, EXPERTS), 256, 0, stream>>>(w1, w1t, DIMC, HID);
    transpose_bf16<<<dim3(DIMC / 64, HID / 64, EXPERTS), 256, 0, stream>>>(w2, w2t, HID, DIMC);
    transpose_split_bf16<<<dim3(2304 / 64, DIMC / 64), 256, 0, stream>>>(qkv_w, qwt_h, qwt_l,
                                                                         DIMC, 2304);
    transpose_split_bf16<<<dim3(DIMC / 64, DIMC / 64), 256, 0, stream>>>(proj_w, pwt_h, pwt_l,
                                                                         DIMC, DIMC);

    ln_kernel_t<0><<<TT, 256, 0, stream>>>(x, ln1_g, ln1_b, xn1_h, xn1_l,
                                           nullptr, nullptr, nullptr, nullptr);

    {
        int nmb = (TT + 63) / 64;                       // 25
        int nwg = nmb * (2304 / 64);                    // 900
        mfma_gemm_split<0><<<nwg, 256, 0, stream>>>(
            xn1_h, xn1_l, qwt_h, qwt_l, qkv_b, nullptr, qkv, zrow, TT, 2304, DIMC, nmb);
    }

    attn_mfma_kernel<<<dim3(BB * HEADS, 4), 512, 0, stream>>>(qkv, ao_h, ao_l);

    {
        int nmb = (TT + 63) / 64;                       // 25
        int nwg = nmb * (DIMC / 64);                    // 300
        mfma_gemm_split<1><<<nwg, 256, 0, stream>>>(
            ao_h, ao_l, pwt_h, pwt_l, proj_b, x, x_res, zrow, TT, DIMC, DIMC, nmb);
    }

    // ln2 with fused gate (logits in fp32, top-2 + softmax + counts)
    ln_kernel_t<1><<<TT, 256, 0, stream>>>(x_res, ln2_g, ln2_b, xn2_bf, nullptr,
                                           gate_w, tok_e, tok_g, counts);

    offsets_kernel<<<1, 64, 0, stream>>>(counts, offsets, cursor);

    fill_kernel<<<(TT + 255) / 256, 256, 0, stream>>>(tok_e, cursor, row2tok, tok_row);

    {
        // e1: m97 geometry 128x128, BK=64
        int nxb1 = CAP_ROWS / 128;                      // 33
        int nwg1 = (HID / 128) * nxb1;                  // 24*33 = 792
        mfma_gemm_grouped128<1, 1, 1><<<nwg1, 256, 0, stream>>>(
            xn2_bf, w1t, b1, offsets, row2tok, h, zrow, HID, DIMC, nxb1);

        // e2: 64x128, BK=128 (r17 form)
        int nxb2 = CAP_ROWS / 64;                       // 66
        int nwg2 = (DIMC / 128) * nxb2;                 // 6*66 = 396
        mfma_gemm_grouped<0, 0, 0><<<nwg2, 256, 0, stream>>>(
            h, w2t, nullptr, offsets, row2tok, y, zrow, DIMC, HID, nxb2);
    }

    combine_kernel<<<dim3(TT, 3), 256, 0, stream>>>(x_res, y, b2, tok_e, tok_g, tok_row, out);
}